// Round 22
// baseline (763.294 us; speedup 1.0000x reference)
//
#include <hip/hip_runtime.h>
#include <hip/hip_fp16.h>
#include <math.h>
#include <stdint.h>

#define Bb 64
#define Nn 4096
#define Uu 64
#define RL 4224                         // 64*66
#define NU (Nn*Uu)
#define MATSZ ((size_t)Nn*(size_t)RL)   // elements per feature matrix
#define ELLW 112                        // ELL row capacity (avg nnz ~42), multiple of 4
#define SSTR 104                        // gemm slab k-stride: 96 (3 K-tiles) + 8 bank pad

typedef __attribute__((ext_vector_type(8))) short short8;
typedef __attribute__((ext_vector_type(4))) float f32x4;
typedef unsigned int uint;
typedef unsigned short ushort;

__device__ inline ushort f2h(float f){ return __half_as_ushort(__float2half(f)); }
__device__ inline __half2 u2h(uint u){ union{uint v;__half2 h;} c; c.v=u; return c.h; }
__device__ inline uint h2u(__half2 h){ union{__half2 h;uint v;} c; c.h=h; return c.v; }
__device__ inline float h2f_lo(uint u){ return __half2float(__ushort_as_half((ushort)(u & 0xffffu))); }
__device__ inline float h2f_hi(uint u){ return __half2float(__ushort_as_half((ushort)(u >> 16))); }

// ---------------- ELL extraction: entry = (fp16(val)<<16) | (col<<4), pad to 4 ----------------
__global__ __launch_bounds__(256) void k_fill(const float* __restrict__ sup,
                                              uint* __restrict__ pkv, int* __restrict__ rcnt) {
  const int lane = threadIdx.x & 63;
  const int row = blockIdx.x * 4 + (threadIdx.x >> 6);
  const float* rp = sup + (size_t)row * Nn;
  uint* outp = pkv + (size_t)row * ELLW;
  const unsigned long long lt = (1ull << lane) - 1ull;
  int off = 0;
  for (int j0 = 0; j0 < Nn; j0 += 64) {
    float v = rp[j0 + lane];
    unsigned long long m = __ballot(v != 0.0f);
    if (v != 0.0f) {
      int pos = off + (int)__popcll(m & lt);
      if (pos < ELLW) outp[pos] = ((uint)f2h(v) << 16) | ((uint)(j0 + lane) << 4);
    }
    off += (int)__popcll(m);
  }
  if (off > ELLW) off = ELLW;
  const int c4 = (off + 3) & ~3;
  if (lane < c4 - off) outp[off + lane] = 0u;    // val=0: contributes nothing
  if (lane == 0) rcnt[row] = c4;
}

// ---------------- nnz counting sort per support: rcp[slot] = (c4<<16) | orig_row ----------------
__global__ __launch_bounds__(1024) void k_perm(const int* __restrict__ rcnt, uint* __restrict__ rcp) {
  __shared__ int base[32];
  const int s = blockIdx.x, t = threadIdx.x;
  if (t < 32) base[t] = 0;
  __syncthreads();
  for (int r = t; r < 4096; r += 1024) atomicAdd(&base[rcnt[s*4096 + r] >> 2], 1);
  __syncthreads();
  if (t == 0) { int acc = 0; for (int i = 0; i < 32; ++i) { int h = base[i]; base[i] = acc; acc += h; } }
  __syncthreads();
  for (int r = t; r < 4096; r += 1024) {
    const int c4 = rcnt[s*4096 + r];
    const int pos = atomicAdd(&base[c4 >> 2], 1);
    rcp[s*4096 + pos] = ((uint)c4 << 16) | (uint)r;
  }
}

// ---------------- ELL transpose -> columnar pT[i][8192], PERMUTED slot order ----------------
__global__ __launch_bounds__(256) void k_tr(const uint* __restrict__ pkv, const uint* __restrict__ rcp,
                                            uint* __restrict__ pT) {
  __shared__ uint tile[64*113];
  __shared__ int rows_l[64];
  const int g = blockIdx.x, t = threadIdx.x;     // 128 blocks x 64 slots
  const int s = g >> 6;
  if (t < 64) rows_l[t] = (s << 12) | (int)(rcp[g*64 + t] & 0xffffu);
  __syncthreads();
  for (int idx = t; idx < 64*ELLW; idx += 256) {
    const int r = idx / ELLW, i = idx - r*ELLW;
    tile[r*113 + i] = pkv[(size_t)rows_l[r]*ELLW + i];
  }
  __syncthreads();
  for (int idx = t; idx < 64*ELLW; idx += 256) {
    const int i = idx >> 6, r = idx & 63;
    pT[(size_t)i*8192 + g*64 + r] = tile[r*113 + i];
  }
}

// ---------------- x0 = [inputs | hx] fp16 in [n][b][f] + hxh fp16 copy ----------------
__global__ __launch_bounds__(256) void k_bx0(const float* __restrict__ inp, const float* __restrict__ hx,
                                             ushort* __restrict__ x0, ushort* __restrict__ hxh) {
  const int n = blockIdx.x;
  const int b = threadIdx.x >> 2, q = threadIdx.x & 3;
  const float* hp = hx + (size_t)b*NU + (size_t)n*Uu + q*16;
  ushort* xp = x0 + (size_t)n*RL + b*66;
  ushort* hh = hxh + (size_t)b*NU + (size_t)n*Uu + q*16;
  #pragma unroll
  for (int i = 0; i < 4; ++i) {
    const float4 v = *(const float4*)&hp[i*4];
    const uint lo = (uint)f2h(v.x) | ((uint)f2h(v.y) << 16);
    const uint hi = (uint)f2h(v.z) | ((uint)f2h(v.w) << 16);
    const int o = 2 + q*16 + i*4;
    *(uint*)&xp[o]     = lo;
    *(uint*)&xp[o + 2] = hi;
    *(uint*)&hh[i*4]     = lo;
    *(uint*)&hh[i*4 + 2] = hi;
  }
  if (q == 0) {
    const float2 iv = *(const float2*)&inp[(size_t)b*(size_t)(Nn*2) + (size_t)n*2];
    *(uint*)&xp[0] = (uint)f2h(iv.x) | ((uint)f2h(iv.y) << 16);
  }
}

#define DSRD(E) (*(const uint4*)(slb + ((E) & 0xfff0u)))

#define FMA16(EA, EB, EC, ED, W0, W1, W2, W3)                                      \
  {                                                                                \
    const __half2 av0 = u2h(__builtin_amdgcn_perm(EA, EA, 0x03020302u));           \
    const __half2 av1 = u2h(__builtin_amdgcn_perm(EB, EB, 0x03020302u));           \
    const __half2 av2 = u2h(__builtin_amdgcn_perm(EC, EC, 0x03020302u));           \
    const __half2 av3 = u2h(__builtin_amdgcn_perm(ED, ED, 0x03020302u));           \
    a01 = __hfma2(av0, u2h(W0.x), a01); a23 = __hfma2(av0, u2h(W0.y), a23);        \
    a45 = __hfma2(av0, u2h(W0.z), a45); a67 = __hfma2(av0, u2h(W0.w), a67);        \
    a01 = __hfma2(av1, u2h(W1.x), a01); a23 = __hfma2(av1, u2h(W1.y), a23);        \
    a45 = __hfma2(av1, u2h(W1.z), a45); a67 = __hfma2(av1, u2h(W1.w), a67);        \
    a01 = __hfma2(av2, u2h(W2.x), a01); a23 = __hfma2(av2, u2h(W2.y), a23);        \
    a45 = __hfma2(av2, u2h(W2.z), a45); a67 = __hfma2(av2, u2h(W2.w), a67);        \
    a01 = __hfma2(av3, u2h(W3.x), a01); a23 = __hfma2(av3, u2h(W3.y), a23);        \
    a45 = __hfma2(av3, u2h(W3.z), a45); a67 = __hfma2(av3, u2h(W3.w), a67);        \
  }

#define WALK_ROW(RB)                                                               \
  {                                                                                \
    const uint rc = rcp[RB];                                                       \
    const int n4 = (int)(rc >> 18);                                                \
    const int row = (int)(rc & 0xffffu);                                           \
    const uint* pp = pT + (RB);                                                    \
    __half2 a01 = u2h(0), a23 = u2h(0), a45 = u2h(0), a67 = u2h(0);                \
    uint e0=pp[0], e1=pp[8192], e2=pp[16384], e3=pp[24576]; pp += 32768;           \
    uint4 w0=DSRD(e0), w1=DSRD(e1), w2=DSRD(e2), w3=DSRD(e3);                      \
    uint f0=0, f1=0, f2=0, f3=0;                                                   \
    if (n4 > 1) { f0=pp[0]; f1=pp[8192]; f2=pp[16384]; f3=pp[24576]; pp += 32768; }\
    for (int i = 1; i < n4; ++i) {                                                 \
      const uint g0=pp[0], g1=pp[8192], g2=pp[16384], g3=pp[24576]; pp += 32768;   \
      const uint4 v0=DSRD(f0), v1=DSRD(f1), v2=DSRD(f2), v3=DSRD(f3);              \
      FMA16(e0, e1, e2, e3, w0, w1, w2, w3);                                       \
      e0=f0; e1=f1; e2=f2; e3=f3; f0=g0; f1=g1; f2=g2; f3=g3;                      \
      w0=v0; w1=v1; w2=v2; w3=v3;                                                  \
    }                                                                              \
    FMA16(e0, e1, e2, e3, w0, w1, w2, w3);                                         \
    uint4 o;                                                                       \
    if (PASS2) {                                                                   \
      const uint4 xv = *(const uint4*)&xsub[(size_t)row*RL + c0];                  \
      o.x = h2u(__hsub2(__hadd2(a01, a01), u2h(xv.x)));                            \
      o.y = h2u(__hsub2(__hadd2(a23, a23), u2h(xv.y)));                            \
      o.z = h2u(__hsub2(__hadd2(a45, a45), u2h(xv.z)));                            \
      o.w = h2u(__hsub2(__hadd2(a67, a67), u2h(xv.w)));                            \
    } else {                                                                       \
      o.x = h2u(a01); o.y = h2u(a23); o.z = h2u(a45); o.w = h2u(a67);              \
    }                                                                              \
    *(uint4*)&yo[(size_t)row*RL] = o;                                              \
  }

// ---------------- SpMM: fp16 + columnar ELL (sorted slots) ----------------
template<bool PASS2>
__global__ __launch_bounds__(1024, 8) void k_spmm(const ushort* __restrict__ xin,
                                                  const ushort* __restrict__ xsub,
                                                  ushort* __restrict__ yout,
                                                  const uint* __restrict__ rcp,
                                                  const uint* __restrict__ pT) {
  __shared__ ushort slab[4096*8];                        // 64 KiB, 16B rows
  const char* slb = (const char*)slab;
  const int t = threadIdx.x, b = blockIdx.x;
  #pragma unroll 1
  for (int task = 0; task < 2; ++task) {
    int unit, r0, nr;
    if (task == 0) { unit = ((b & 7) << 6) + (b >> 3); r0 = 0; nr = 4096; }
    else           { unit = 512 + (b >> 5); r0 = (b & 31) * 128; nr = 128; }
    const int c0 = unit * 8;
    #pragma unroll 1
    for (int s = 0; s < 2; ++s) {
      if (PASS2 || s == 0) {                             // pass1 shares the x slab
        if (task | s) __syncthreads();                   // walkers done before restage
        const ushort* src = xin + (PASS2 ? (size_t)s * MATSZ : (size_t)0) + c0;
        #pragma unroll
        for (int it = 0; it < 4; ++it) {
          const int j = it * 1024 + t;
          *(uint4*)&slab[j * 8] = *(const uint4*)&src[(size_t)j * RL];
        }
        __syncthreads();
      }
      const int sb = s << 12;
      ushort* yo = yout + (size_t)s * MATSZ + c0;
      #pragma unroll 1
      for (int r = r0 + t; r < r0 + nr; r += 1024) {     // 1 lane per sorted slot
        const int rb = sb + r;
        WALK_ROW(rb);
      }
    }
  }
}

// ---------------- W pre-pack, slab order: T = m*3+kt, k_in_slab f = kt*32+koffu+i ----------------
__global__ __launch_bounds__(256) void k_wpack(const float* __restrict__ W1, const float* __restrict__ W2,
                                               ushort* __restrict__ Wp1, ushort* __restrict__ Wp2) {
  const int tid = blockIdx.x*256 + threadIdx.x;      // grid 360 -> 92160
  const int i = tid & 7, l = (tid >> 3) & 63;
  const int koffu = (l >> 4) * 8;
  if (tid < 61440) {
    const int g = tid >> 9, tt = g / 15, T = g % 15;
    const int m = T / 3, kt = T % 3;
    const int f = kt*32 + koffu + i;
    const int c = tt*16 + (l & 15);
    Wp1[tid] = (f < 66) ? f2h(W1[(size_t)(f*5 + m)*128 + c]) : (ushort)0;
  } else {
    const int t2 = tid - 61440;
    const int g = t2 >> 9, tt = g / 15, T = g % 15;
    const int m = T / 3, kt = T % 3;
    const int f = kt*32 + koffu + i;
    const int c = tt*16 + (l & 15);
    Wp2[t2] = (f < 66) ? f2h(W2[(size_t)(f*5 + m)*64 + c]) : (ushort)0;
  }
}

// uint2 (4 ushort) scatter into slab: straddles b-boundary only when f0 == 64
#define STAGE_W2(DST, J2, V)                                                       \
  {                                                                                \
    const int q_ = 4*(J2); const int b_ = q_/66; const int f_ = q_ - 66*b_;        \
    if (f_ < 64) { *(uint*)&(DST)[b_*SSTR+f_] = (V).x; *(uint*)&(DST)[b_*SSTR+f_+2] = (V).y; } \
    else         { *(uint*)&(DST)[b_*SSTR+64] = (V).x; *(uint*)&(DST)[(b_+1)*SSTR] = (V).y; }  \
  }

// ---------------- gconv1 output GEMM (slab-pipelined, MFMA f16), sigmoid + r*hx + u ----------------
__global__ __launch_bounds__(256, 6) void k_gemm1(const ushort* __restrict__ x0, const ushort* __restrict__ y1,
                                                  const ushort* __restrict__ y2, const ushort* __restrict__ Wp,
                                                  const float* __restrict__ bias, const ushort* __restrict__ hxh,
                                                  ushort* __restrict__ x0w, ushort* __restrict__ ubuf) {
  __shared__ ushort Xs[2][64*SSTR];                // 26.6 KiB -> 6 blocks/CU
  const int n = blockIdx.x, t = threadIdx.x;
  for (int q = t; q < 2*64*SSTR/4; q += 256) ((unsigned long long*)Xs)[q] = 0ull;  // pads stay 0
  __syncthreads();
  const ushort* mats[5] = { x0 + (size_t)n*RL, y1 + (size_t)n*RL, y2 + (size_t)n*RL,
                            y1 + MATSZ + (size_t)n*RL, y2 + MATSZ + (size_t)n*RL };
  {
    const ushort* mp = mats[0];
    for (int j = t; j < 1056; j += 256) { const uint2 v = *(const uint2*)&mp[4*j]; STAGE_W2(Xs[0], j, v); }
  }
  __syncthreads();
  const int w = t >> 6, l = t & 63;
  const int b0 = w * 16;
  const int arow = b0 + (l & 15), koffu = (l >> 4) * 8;
  f32x4 acc[8];
  #pragma unroll
  for (int i = 0; i < 8; ++i) acc[i] = (f32x4){0.f,0.f,0.f,0.f};
  #pragma unroll
  for (int m = 0; m < 5; ++m) {
    const int cur = m & 1;
    uint2 p0={0,0},p1={0,0},p2={0,0},p3={0,0},p4={0,0};
    if (m < 4) {                                   // prefetch next slab (uint2)
      const ushort* mp = mats[m+1];
      p0 = *(const uint2*)&mp[4*t];         p1 = *(const uint2*)&mp[4*(t+256)];
      p2 = *(const uint2*)&mp[4*(t+512)];   p3 = *(const uint2*)&mp[4*(t+768)];
      if (t < 32) p4 = *(const uint2*)&mp[4*(t+1024)];
    }
    #pragma unroll
    for (int kt = 0; kt < 3; ++kt) {
      const short8 af = *(const short8*)&Xs[cur][arow*SSTR + kt*32 + koffu];
      const int T = m*3 + kt;
      #pragma unroll
      for (int tt = 0; tt < 8; ++tt) {
        const short8 bf = *(const short8*)&Wp[(((size_t)tt*15 + T)*64 + l)*8];
        acc[tt] = __builtin_amdgcn_mfma_f32_16x16x32_f16(af, bf, acc[tt], 0, 0, 0);
      }
    }
    if (m < 4) {
      ushort* nb = Xs[cur ^ 1];
      STAGE_W2(nb, t,      p0); STAGE_W2(nb, t+256, p1);
      STAGE_W2(nb, t+512,  p2); STAGE_W2(nb, t+768, p3);
      if (t < 32) STAGE_W2(nb, t+1024, p4);
    }
    __syncthreads();
  }
  // phase 1: activation -> LDS Os[b][o], fp16, stride 132
  ushort* Os = (ushort*)Xs;
  const int rg = (l >> 4) * 4;
  #pragma unroll
  for (int tt = 0; tt < 8; ++tt) {
    const int o = tt*16 + (l & 15);
    const float bs = bias[o];
    #pragma unroll
    for (int r = 0; r < 4; ++r) {
      const int b = b0 + rg + r;
      const float v = acc[tt][r] + bs;
      Os[b*132 + o] = f2h(1.0f / (1.0f + __expf(-v)));
    }
  }
  __syncthreads();
  // phase 2: coalesced outputs; q==0 lane rewrites the 2-ushort inp hole -> dense rows
  {
    const int b = t >> 2, q = t & 3;
    const ushort* hp = hxh + (size_t)b*NU + (size_t)n*Uu + q*16;
    ushort* xw = x0w + (size_t)n*RL + b*66 + 2 + q*16;
    const ushort* os = &Os[b*132 + q*16];
    uint hole = 0;
    if (q == 0) hole = *(const uint*)&x0[(size_t)n*RL + b*66];
    #pragma unroll
    for (int i = 0; i < 4; ++i) {                  // r gate: x0w = sg * hx
      const uint2 hv = *(const uint2*)&hp[i*4];
      const float h0 = h2f_lo(hv.x), h1 = h2f_hi(hv.x), h2 = h2f_lo(hv.y), h3 = h2f_hi(hv.y);
      const float s0 = __half2float(__ushort_as_half(os[i*4+0]));
      const float s1 = __half2float(__ushort_as_half(os[i*4+1]));
      const float s2 = __half2float(__ushort_as_half(os[i*4+2]));
      const float s3 = __half2float(__ushort_as_half(os[i*4+3]));
      *(uint*)&xw[i*4]     = (uint)f2h(s0*h0) | ((uint)f2h(s1*h1) << 16);
      *(uint*)&xw[i*4 + 2] = (uint)f2h(s2*h2) | ((uint)f2h(s3*h3) << 16);
    }
    if (q == 0) *(uint*)&x0w[(size_t)n*RL + b*66] = hole;   // same value, dense line coverage
    ushort* uw = ubuf + (size_t)b*NU + (size_t)n*Uu + q*16;
    const ushort* os2 = &Os[b*132 + 64 + q*16];
    #pragma unroll
    for (int i = 0; i < 8; ++i) {                  // u gate
      *(uint*)&uw[i*2] = (uint)os2[i*2] | ((uint)os2[i*2+1] << 16);
    }
  }
}

// ---------------- gconv2 output GEMM (slab-pipelined, MFMA f16), tanh + final gate ----------------
__global__ __launch_bounds__(256, 6) void k_gemm2(const ushort* __restrict__ x0, const ushort* __restrict__ y1,
                                                  const ushort* __restrict__ y2, const ushort* __restrict__ Wp,
                                                  const float* __restrict__ bias, const ushort* __restrict__ hxh,
                                                  const ushort* __restrict__ ubuf, float* __restrict__ out) {
  __shared__ ushort Xs[2][64*SSTR];
  const int n = blockIdx.x, t = threadIdx.x;
  for (int q = t; q < 2*64*SSTR/4; q += 256) ((unsigned long long*)Xs)[q] = 0ull;
  __syncthreads();
  const ushort* mats[5] = { x0 + (size_t)n*RL, y1 + (size_t)n*RL, y2 + (size_t)n*RL,
                            y1 + MATSZ + (size_t)n*RL, y2 + MATSZ + (size_t)n*RL };
  {
    const ushort* mp = mats[0];
    for (int j = t; j < 1056; j += 256) { const uint2 v = *(const uint2*)&mp[4*j]; STAGE_W2(Xs[0], j, v); }
  }
  __syncthreads();
  const int w = t >> 6, l = t & 63;
  const int b0 = w * 16;
  const int arow = b0 + (l & 15), koffu = (l >> 4) * 8;
  f32x4 acc[4];
  #pragma unroll
  for (int i = 0; i < 4; ++i) acc[i] = (f32x4){0.f,0.f,0.f,0.f};
  #pragma unroll
  for (int m = 0; m < 5; ++m) {
    const int cur = m & 1;
    uint2 p0={0,0},p1={0,0},p2={0,0},p3={0,0},p4={0,0};
    if (m < 4) {
      const ushort* mp = mats[m+1];
      p0 = *(const uint2*)&mp[4*t];         p1 = *(const uint2*)&mp[4*(t+256)];
      p2 = *(const uint2*)&mp[4*(t+512)];   p3 = *(const uint2*)&mp[4*(t+768)];
      if (t < 32) p4 = *(const uint2*)&mp[4*(t+1024)];
    }
    #pragma unroll
    for (int kt = 0; kt < 3; ++kt) {
      const short8 af = *(const short8*)&Xs[cur][arow*SSTR + kt*32 + koffu];
      const int T = m*3 + kt;
      #pragma unroll
      for (int tt = 0; tt < 4; ++tt) {
        const short8 bf = *(const short8*)&Wp[(((size_t)tt*15 + T)*64 + l)*8];
        acc[tt] = __builtin_amdgcn_mfma_f32_16x16x32_f16(af, bf, acc[tt], 0, 0, 0);
      }
    }
    if (m < 4) {
      ushort* nb = Xs[cur ^ 1];
      STAGE_W2(nb, t,      p0); STAGE_W2(nb, t+256, p1);
      STAGE_W2(nb, t+512,  p2); STAGE_W2(nb, t+768, p3);
      if (t < 32) STAGE_W2(nb, t+1024, p4);
    }
    __syncthreads();
  }
  // phase 1: c = tanh(acc+bias) -> LDS Os[b][o], fp16, stride 68
  ushort* Os = (ushort*)Xs;
  const int rg = (l >> 4) * 4;
  #pragma unroll
  for (int tt = 0; tt < 4; ++tt) {
    const int o = tt*16 + (l & 15);
    const float bs = bias[o];
    #pragma unroll
    for (int r = 0; r < 4; ++r) {
      const int b = b0 + rg + r;
      Os[b*68 + o] = f2h(tanhf(acc[tt][r] + bs));
    }
  }
  __syncthreads();
  // phase 2: out = u*h + (1-u)*c, coalesced float4 stores (h from fp16 hxh)
  {
    const int b = t >> 2, q = t & 3;
    const ushort* hp = hxh + (size_t)b*NU + (size_t)n*Uu + q*16;
    const ushort* up = ubuf + (size_t)b*NU + (size_t)n*Uu + q*16;
    float* op = out + (size_t)b*NU + (size_t)n*Uu + q*16;
    const ushort* os = &Os[b*68 + q*16];
    #pragma unroll
    for (int i = 0; i < 4; ++i) {
      const uint2 hv = *(const uint2*)&hp[i*4];
      const float h0 = h2f_lo(hv.x), h1 = h2f_hi(hv.x), h2 = h2f_lo(hv.y), h3 = h2f_hi(hv.y);
      const uint u01 = *(const uint*)&up[i*4];
      const uint u23 = *(const uint*)&up[i*4 + 2];
      const float u0 = h2f_lo(u01), u1 = h2f_hi(u01), u2 = h2f_lo(u23), u3 = h2f_hi(u23);
      float4 o4;
      o4.x = u0*h0 + (1.0f - u0)*__half2float(__ushort_as_half(os[i*4+0]));
      o4.y = u1*h1 + (1.0f - u1)*__half2float(__ushort_as_half(os[i*4+1]));
      o4.z = u2*h2 + (1.0f - u2)*__half2float(__ushort_as_half(os[i*4+2]));
      o4.w = u3*h3 + (1.0f - u3)*__half2float(__ushort_as_half(os[i*4+3]));
      *(float4*)&op[i*4] = o4;
    }
  }
}

extern "C" void kernel_launch(void* const* d_in, const int* in_sizes, int n_in,
                              void* d_out, int out_size, void* d_ws, size_t ws_size,
                              hipStream_t stream) {
  const float* inp = (const float*)d_in[0];
  const float* hx  = (const float*)d_in[1];
  const float* sup = (const float*)d_in[2];
  const float* ruW = (const float*)d_in[3];
  const float* ruB = (const float*)d_in[4];
  const float* gW  = (const float*)d_in[5];
  const float* gB  = (const float*)d_in[6];
  float* out = (float*)d_out;

  // workspace: x0 | y1[2] | y2[2] | u | hxh | Wpk | ELL(row) | ELL(col)+pad | rcnt | rcp
  ushort* x0   = (ushort*)d_ws;
  ushort* y1   = x0 + MATSZ;
  ushort* y2   = y1 + 2*MATSZ;
  ushort* ubuf = y2 + 2*MATSZ;
  ushort* hxh  = ubuf + (size_t)Bb*NU;
  ushort* Wp1  = hxh + (size_t)Bb*NU;
  ushort* Wp2  = Wp1 + 61440;
  uint* pkv  = (uint*)(Wp2 + 30720);
  uint* pT   = pkv + (size_t)8192*ELLW;
  int*  rcnt = (int*)(pT + (size_t)8192*(ELLW + 4));   // +4: prefetch overrun pad
  uint* rcp  = (uint*)(rcnt + 8192);

  k_fill<<<2048, 256, 0, stream>>>(sup, pkv, rcnt);
  k_perm<<<2, 1024, 0, stream>>>(rcnt, rcp);
  k_tr<<<128, 256, 0, stream>>>(pkv, rcp, pT);
  k_wpack<<<360, 256, 0, stream>>>(ruW, gW, Wp1, Wp2);
  k_bx0<<<Nn, 256, 0, stream>>>(inp, hx, x0, hxh);

  // gconv1
  k_spmm<false><<<512, 1024, 0, stream>>>(x0, nullptr, y1, rcp, pT);
  k_spmm<true ><<<512, 1024, 0, stream>>>(y1, x0,      y2, rcp, pT);
  k_gemm1<<<Nn, 256, 0, stream>>>(x0, y1, y2, Wp1, ruB, hxh, x0, ubuf);
  // gconv2 (x0 state slots now hold fp16(r*hx))
  k_spmm<false><<<512, 1024, 0, stream>>>(x0, nullptr, y1, rcp, pT);
  k_spmm<true ><<<512, 1024, 0, stream>>>(y1, x0,      y2, rcp, pT);
  k_gemm2<<<Nn, 256, 0, stream>>>(x0, y1, y2, Wp2, gB, hxh, ubuf, out);
}

// Round 23
// 726.402 us; speedup vs baseline: 1.0508x; 1.0508x over previous
//
#include <hip/hip_runtime.h>
#include <hip/hip_fp16.h>
#include <math.h>
#include <stdint.h>

#define Bb 64
#define Nn 4096
#define Uu 64
#define RL 4224                         // 64*66
#define NU (Nn*Uu)
#define MATSZ ((size_t)Nn*(size_t)RL)   // elements per feature matrix
#define ELLW 112                        // ELL row capacity (avg nnz ~42), multiple of 4
#define SSTR 104                        // gemm slab k-stride: 96 (3 K-tiles) + 8 bank pad

typedef __attribute__((ext_vector_type(8))) short short8;
typedef __attribute__((ext_vector_type(4))) float f32x4;
typedef unsigned int uint;
typedef unsigned short ushort;

__device__ inline ushort f2h(float f){ return __half_as_ushort(__float2half(f)); }
__device__ inline __half2 u2h(uint u){ union{uint v;__half2 h;} c; c.v=u; return c.h; }
__device__ inline uint h2u(__half2 h){ union{__half2 h;uint v;} c; c.h=h; return c.v; }
__device__ inline float h2f_lo(uint u){ return __half2float(__ushort_as_half((ushort)(u & 0xffffu))); }
__device__ inline float h2f_hi(uint u){ return __half2float(__ushort_as_half((ushort)(u >> 16))); }

// ---------------- ELL extraction: entry = (fp16(val)<<16) | (col<<4), pad to 4 ----------------
__global__ __launch_bounds__(256) void k_fill(const float* __restrict__ sup,
                                              uint* __restrict__ pkv, int* __restrict__ rcnt) {
  const int lane = threadIdx.x & 63;
  const int row = blockIdx.x * 4 + (threadIdx.x >> 6);
  const float* rp = sup + (size_t)row * Nn;
  uint* outp = pkv + (size_t)row * ELLW;
  const unsigned long long lt = (1ull << lane) - 1ull;
  int off = 0;
  for (int j0 = 0; j0 < Nn; j0 += 64) {
    float v = rp[j0 + lane];
    unsigned long long m = __ballot(v != 0.0f);
    if (v != 0.0f) {
      int pos = off + (int)__popcll(m & lt);
      if (pos < ELLW) outp[pos] = ((uint)f2h(v) << 16) | ((uint)(j0 + lane) << 4);
    }
    off += (int)__popcll(m);
  }
  if (off > ELLW) off = ELLW;
  const int c4 = (off + 3) & ~3;
  if (lane < c4 - off) outp[off + lane] = 0u;    // val=0: contributes nothing
  if (lane == 0) rcnt[row] = c4;
}

// ---------------- nnz counting sort per support: rcp[slot] = (c4<<16) | orig_row ----------------
__global__ __launch_bounds__(1024) void k_perm(const int* __restrict__ rcnt, uint* __restrict__ rcp) {
  __shared__ int base[32];
  const int s = blockIdx.x, t = threadIdx.x;
  if (t < 32) base[t] = 0;
  __syncthreads();
  for (int r = t; r < 4096; r += 1024) atomicAdd(&base[rcnt[s*4096 + r] >> 2], 1);
  __syncthreads();
  if (t == 0) { int acc = 0; for (int i = 0; i < 32; ++i) { int h = base[i]; base[i] = acc; acc += h; } }
  __syncthreads();
  for (int r = t; r < 4096; r += 1024) {
    const int c4 = rcnt[s*4096 + r];
    const int pos = atomicAdd(&base[c4 >> 2], 1);
    rcp[s*4096 + pos] = ((uint)c4 << 16) | (uint)r;
  }
}

// ---------------- ELL transpose -> columnar pT[i][8192], PERMUTED slot order ----------------
__global__ __launch_bounds__(256) void k_tr(const uint* __restrict__ pkv, const uint* __restrict__ rcp,
                                            uint* __restrict__ pT) {
  __shared__ uint tile[64*113];
  __shared__ int rows_l[64];
  const int g = blockIdx.x, t = threadIdx.x;     // 128 blocks x 64 slots
  const int s = g >> 6;
  if (t < 64) rows_l[t] = (s << 12) | (int)(rcp[g*64 + t] & 0xffffu);
  __syncthreads();
  for (int idx = t; idx < 64*ELLW; idx += 256) {
    const int r = idx / ELLW, i = idx - r*ELLW;
    tile[r*113 + i] = pkv[(size_t)rows_l[r]*ELLW + i];
  }
  __syncthreads();
  for (int idx = t; idx < 64*ELLW; idx += 256) {
    const int i = idx >> 6, r = idx & 63;
    pT[(size_t)i*8192 + g*64 + r] = tile[r*113 + i];
  }
}

// ---------------- x0 = [inputs | hx] fp16 in [n][b][f] + hxh fp16 copy ----------------
__global__ __launch_bounds__(256) void k_bx0(const float* __restrict__ inp, const float* __restrict__ hx,
                                             ushort* __restrict__ x0, ushort* __restrict__ hxh) {
  const int n = blockIdx.x;
  const int b = threadIdx.x >> 2, q = threadIdx.x & 3;
  const float* hp = hx + (size_t)b*NU + (size_t)n*Uu + q*16;
  ushort* xp = x0 + (size_t)n*RL + b*66;
  ushort* hh = hxh + (size_t)b*NU + (size_t)n*Uu + q*16;
  #pragma unroll
  for (int i = 0; i < 4; ++i) {
    const float4 v = *(const float4*)&hp[i*4];
    const uint lo = (uint)f2h(v.x) | ((uint)f2h(v.y) << 16);
    const uint hi = (uint)f2h(v.z) | ((uint)f2h(v.w) << 16);
    const int o = 2 + q*16 + i*4;
    *(uint*)&xp[o]     = lo;
    *(uint*)&xp[o + 2] = hi;
    *(uint*)&hh[i*4]     = lo;
    *(uint*)&hh[i*4 + 2] = hi;
  }
  if (q == 0) {
    const float2 iv = *(const float2*)&inp[(size_t)b*(size_t)(Nn*2) + (size_t)n*2];
    *(uint*)&xp[0] = (uint)f2h(iv.x) | ((uint)f2h(iv.y) << 16);
  }
}

#define DSRD(E) (*(const uint4*)(slb + ((E) & 0xfff0u)))

#define FMA16(EA, EB, EC, ED, W0, W1, W2, W3)                                      \
  {                                                                                \
    const __half2 av0 = u2h(__builtin_amdgcn_perm(EA, EA, 0x03020302u));           \
    const __half2 av1 = u2h(__builtin_amdgcn_perm(EB, EB, 0x03020302u));           \
    const __half2 av2 = u2h(__builtin_amdgcn_perm(EC, EC, 0x03020302u));           \
    const __half2 av3 = u2h(__builtin_amdgcn_perm(ED, ED, 0x03020302u));           \
    a01 = __hfma2(av0, u2h(W0.x), a01); a23 = __hfma2(av0, u2h(W0.y), a23);        \
    a45 = __hfma2(av0, u2h(W0.z), a45); a67 = __hfma2(av0, u2h(W0.w), a67);        \
    a01 = __hfma2(av1, u2h(W1.x), a01); a23 = __hfma2(av1, u2h(W1.y), a23);        \
    a45 = __hfma2(av1, u2h(W1.z), a45); a67 = __hfma2(av1, u2h(W1.w), a67);        \
    a01 = __hfma2(av2, u2h(W2.x), a01); a23 = __hfma2(av2, u2h(W2.y), a23);        \
    a45 = __hfma2(av2, u2h(W2.z), a45); a67 = __hfma2(av2, u2h(W2.w), a67);        \
    a01 = __hfma2(av3, u2h(W3.x), a01); a23 = __hfma2(av3, u2h(W3.y), a23);        \
    a45 = __hfma2(av3, u2h(W3.z), a45); a67 = __hfma2(av3, u2h(W3.w), a67);        \
  }

#define WALK_ROW(RB)                                                               \
  {                                                                                \
    const uint rc = rcp[RB];                                                       \
    const int n4 = (int)(rc >> 18);                                                \
    const int row = (int)(rc & 0xffffu);                                           \
    const uint* pp = pT + (RB);                                                    \
    __half2 a01 = u2h(0), a23 = u2h(0), a45 = u2h(0), a67 = u2h(0);                \
    uint e0=pp[0], e1=pp[8192], e2=pp[16384], e3=pp[24576]; pp += 32768;           \
    uint4 w0=DSRD(e0), w1=DSRD(e1), w2=DSRD(e2), w3=DSRD(e3);                      \
    uint f0=0, f1=0, f2=0, f3=0;                                                   \
    if (n4 > 1) { f0=pp[0]; f1=pp[8192]; f2=pp[16384]; f3=pp[24576]; pp += 32768; }\
    for (int i = 1; i < n4; ++i) {                                                 \
      const uint g0=pp[0], g1=pp[8192], g2=pp[16384], g3=pp[24576]; pp += 32768;   \
      const uint4 v0=DSRD(f0), v1=DSRD(f1), v2=DSRD(f2), v3=DSRD(f3);              \
      FMA16(e0, e1, e2, e3, w0, w1, w2, w3);                                       \
      e0=f0; e1=f1; e2=f2; e3=f3; f0=g0; f1=g1; f2=g2; f3=g3;                      \
      w0=v0; w1=v1; w2=v2; w3=v3;                                                  \
    }                                                                              \
    FMA16(e0, e1, e2, e3, w0, w1, w2, w3);                                         \
    uint4 o;                                                                       \
    if (PASS2) {                                                                   \
      const uint4 xv = *(const uint4*)&xsub[(size_t)row*RL + c0];                  \
      o.x = h2u(__hsub2(__hadd2(a01, a01), u2h(xv.x)));                            \
      o.y = h2u(__hsub2(__hadd2(a23, a23), u2h(xv.y)));                            \
      o.z = h2u(__hsub2(__hadd2(a45, a45), u2h(xv.z)));                            \
      o.w = h2u(__hsub2(__hadd2(a67, a67), u2h(xv.w)));                            \
    } else {                                                                       \
      o.x = h2u(a01); o.y = h2u(a23); o.z = h2u(a45); o.w = h2u(a67);              \
    }                                                                              \
    *(uint4*)&yo[(size_t)row*RL] = o;                                              \
  }

// ---------------- SpMM: fp16 + columnar ELL (sorted slots) ----------------
template<bool PASS2>
__global__ __launch_bounds__(1024, 8) void k_spmm(const ushort* __restrict__ xin,
                                                  const ushort* __restrict__ xsub,
                                                  ushort* __restrict__ yout,
                                                  const uint* __restrict__ rcp,
                                                  const uint* __restrict__ pT) {
  __shared__ ushort slab[4096*8];                        // 64 KiB, 16B rows
  const char* slb = (const char*)slab;
  const int t = threadIdx.x, b = blockIdx.x;
  #pragma unroll 1
  for (int task = 0; task < 2; ++task) {
    int unit, r0, nr;
    if (task == 0) { unit = ((b & 7) << 6) + (b >> 3); r0 = 0; nr = 4096; }
    else           { unit = 512 + (b >> 5); r0 = (b & 31) * 128; nr = 128; }
    const int c0 = unit * 8;
    #pragma unroll 1
    for (int s = 0; s < 2; ++s) {
      if (PASS2 || s == 0) {                             // pass1 shares the x slab
        if (task | s) __syncthreads();                   // walkers done before restage
        const ushort* src = xin + (PASS2 ? (size_t)s * MATSZ : (size_t)0) + c0;
        #pragma unroll
        for (int it = 0; it < 4; ++it) {
          const int j = it * 1024 + t;
          *(uint4*)&slab[j * 8] = *(const uint4*)&src[(size_t)j * RL];
        }
        __syncthreads();
      }
      const int sb = s << 12;
      ushort* yo = yout + (size_t)s * MATSZ + c0;
      #pragma unroll 1
      for (int r = r0 + t; r < r0 + nr; r += 1024) {     // 1 lane per sorted slot
        const int rb = sb + r;
        WALK_ROW(rb);
      }
    }
  }
}

// ---------------- W pre-pack, slab order: T = m*3+kt, k_in_slab f = kt*32+koffu+i ----------------
__global__ __launch_bounds__(256) void k_wpack(const float* __restrict__ W1, const float* __restrict__ W2,
                                               ushort* __restrict__ Wp1, ushort* __restrict__ Wp2) {
  const int tid = blockIdx.x*256 + threadIdx.x;      // grid 360 -> 92160
  const int i = tid & 7, l = (tid >> 3) & 63;
  const int koffu = (l >> 4) * 8;
  if (tid < 61440) {
    const int g = tid >> 9, tt = g / 15, T = g % 15;
    const int m = T / 3, kt = T % 3;
    const int f = kt*32 + koffu + i;
    const int c = tt*16 + (l & 15);
    Wp1[tid] = (f < 66) ? f2h(W1[(size_t)(f*5 + m)*128 + c]) : (ushort)0;
  } else {
    const int t2 = tid - 61440;
    const int g = t2 >> 9, tt = g / 15, T = g % 15;
    const int m = T / 3, kt = T % 3;
    const int f = kt*32 + koffu + i;
    const int c = tt*16 + (l & 15);
    Wp2[t2] = (f < 66) ? f2h(W2[(size_t)(f*5 + m)*64 + c]) : (ushort)0;
  }
}

// slab source: contiguous 4224 ushorts = 2112 uints; scatter to Xs[b*104+f] (f even -> 4B aligned)
#define STAGE_W(DST, J, V) { const int q_=2*(J), b_=q_/66, f_=q_-66*b_; *(uint*)&(DST)[b_*SSTR+f_] = (V); }

// ---------------- gconv1 output GEMM (slab-pipelined, MFMA f16), sigmoid + r*hx + u ----------------
__global__ __launch_bounds__(256, 6) void k_gemm1(const ushort* __restrict__ x0, const ushort* __restrict__ y1,
                                                  const ushort* __restrict__ y2, const ushort* __restrict__ Wp,
                                                  const float* __restrict__ bias, const ushort* __restrict__ hxh,
                                                  ushort* __restrict__ x0w, ushort* __restrict__ ubuf) {
  __shared__ ushort Xs[2][64*SSTR];                // 26.6 KiB -> 6 blocks/CU
  const int n = blockIdx.x, t = threadIdx.x;
  for (int q = t; q < 2*64*SSTR/4; q += 256) ((unsigned long long*)Xs)[q] = 0ull;  // pads stay 0
  __syncthreads();
  const ushort* mats[5] = { x0 + (size_t)n*RL, y1 + (size_t)n*RL, y2 + (size_t)n*RL,
                            y1 + MATSZ + (size_t)n*RL, y2 + MATSZ + (size_t)n*RL };
  {
    const ushort* mp = mats[0];
    for (int j = t; j < 2112; j += 256) { const uint v = *(const uint*)&mp[2*j]; STAGE_W(Xs[0], j, v); }
  }
  __syncthreads();
  const int w = t >> 6, l = t & 63;
  const int b0 = w * 16;
  const int arow = b0 + (l & 15), koffu = (l >> 4) * 8;
  f32x4 acc[8];
  #pragma unroll
  for (int i = 0; i < 8; ++i) acc[i] = (f32x4){0.f,0.f,0.f,0.f};
  #pragma unroll
  for (int m = 0; m < 5; ++m) {
    const int cur = m & 1;
    uint r0v=0,r1v=0,r2v=0,r3v=0,r4v=0,r5v=0,r6v=0,r7v=0,r8v=0;
    if (m < 4) {                                   // prefetch next slab
      const ushort* mp = mats[m+1];
      r0v = *(const uint*)&mp[2*t];          r1v = *(const uint*)&mp[2*(t+256)];
      r2v = *(const uint*)&mp[2*(t+512)];    r3v = *(const uint*)&mp[2*(t+768)];
      r4v = *(const uint*)&mp[2*(t+1024)];   r5v = *(const uint*)&mp[2*(t+1280)];
      r6v = *(const uint*)&mp[2*(t+1536)];   r7v = *(const uint*)&mp[2*(t+1792)];
      if (t < 64) r8v = *(const uint*)&mp[2*(t+2048)];
    }
    #pragma unroll
    for (int kt = 0; kt < 3; ++kt) {
      const short8 af = *(const short8*)&Xs[cur][arow*SSTR + kt*32 + koffu];
      const int T = m*3 + kt;
      #pragma unroll
      for (int tt = 0; tt < 8; ++tt) {
        const short8 bf = *(const short8*)&Wp[(((size_t)tt*15 + T)*64 + l)*8];
        acc[tt] = __builtin_amdgcn_mfma_f32_16x16x32_f16(af, bf, acc[tt], 0, 0, 0);
      }
    }
    if (m < 4) {
      ushort* nb = Xs[cur ^ 1];
      STAGE_W(nb, t,      r0v); STAGE_W(nb, t+256,  r1v);
      STAGE_W(nb, t+512,  r2v); STAGE_W(nb, t+768,  r3v);
      STAGE_W(nb, t+1024, r4v); STAGE_W(nb, t+1280, r5v);
      STAGE_W(nb, t+1536, r6v); STAGE_W(nb, t+1792, r7v);
      if (t < 64) STAGE_W(nb, t+2048, r8v);
    }
    __syncthreads();
  }
  // phase 1: activation -> LDS Os[b][o], fp16, stride 132
  ushort* Os = (ushort*)Xs;
  const int rg = (l >> 4) * 4;
  #pragma unroll
  for (int tt = 0; tt < 8; ++tt) {
    const int o = tt*16 + (l & 15);
    const float bs = bias[o];
    #pragma unroll
    for (int r = 0; r < 4; ++r) {
      const int b = b0 + rg + r;
      const float v = acc[tt][r] + bs;
      Os[b*132 + o] = f2h(1.0f / (1.0f + __expf(-v)));
    }
  }
  __syncthreads();
  // phase 2: coalesced outputs (hx from fp16 hxh)
  {
    const int b = t >> 2, q = t & 3;
    const ushort* hp = hxh + (size_t)b*NU + (size_t)n*Uu + q*16;
    ushort* xw = x0w + (size_t)n*RL + b*66 + 2 + q*16;
    const ushort* os = &Os[b*132 + q*16];
    #pragma unroll
    for (int i = 0; i < 4; ++i) {                  // r gate: x0w = sg * hx
      const uint2 hv = *(const uint2*)&hp[i*4];
      const float h0 = h2f_lo(hv.x), h1 = h2f_hi(hv.x), h2 = h2f_lo(hv.y), h3 = h2f_hi(hv.y);
      const float s0 = __half2float(__ushort_as_half(os[i*4+0]));
      const float s1 = __half2float(__ushort_as_half(os[i*4+1]));
      const float s2 = __half2float(__ushort_as_half(os[i*4+2]));
      const float s3 = __half2float(__ushort_as_half(os[i*4+3]));
      *(uint*)&xw[i*4]     = (uint)f2h(s0*h0) | ((uint)f2h(s1*h1) << 16);
      *(uint*)&xw[i*4 + 2] = (uint)f2h(s2*h2) | ((uint)f2h(s3*h3) << 16);
    }
    ushort* uw = ubuf + (size_t)b*NU + (size_t)n*Uu + q*16;
    const ushort* os2 = &Os[b*132 + 64 + q*16];
    #pragma unroll
    for (int i = 0; i < 8; ++i) {                  // u gate
      *(uint*)&uw[i*2] = (uint)os2[i*2] | ((uint)os2[i*2+1] << 16);
    }
  }
}

// ---------------- gconv2 output GEMM (slab-pipelined, MFMA f16), tanh + final gate ----------------
__global__ __launch_bounds__(256, 6) void k_gemm2(const ushort* __restrict__ x0, const ushort* __restrict__ y1,
                                                  const ushort* __restrict__ y2, const ushort* __restrict__ Wp,
                                                  const float* __restrict__ bias, const ushort* __restrict__ hxh,
                                                  const ushort* __restrict__ ubuf, float* __restrict__ out) {
  __shared__ ushort Xs[2][64*SSTR];
  const int n = blockIdx.x, t = threadIdx.x;
  for (int q = t; q < 2*64*SSTR/4; q += 256) ((unsigned long long*)Xs)[q] = 0ull;
  __syncthreads();
  const ushort* mats[5] = { x0 + (size_t)n*RL, y1 + (size_t)n*RL, y2 + (size_t)n*RL,
                            y1 + MATSZ + (size_t)n*RL, y2 + MATSZ + (size_t)n*RL };
  {
    const ushort* mp = mats[0];
    for (int j = t; j < 2112; j += 256) { const uint v = *(const uint*)&mp[2*j]; STAGE_W(Xs[0], j, v); }
  }
  __syncthreads();
  const int w = t >> 6, l = t & 63;
  const int b0 = w * 16;
  const int arow = b0 + (l & 15), koffu = (l >> 4) * 8;
  f32x4 acc[4];
  #pragma unroll
  for (int i = 0; i < 4; ++i) acc[i] = (f32x4){0.f,0.f,0.f,0.f};
  #pragma unroll
  for (int m = 0; m < 5; ++m) {
    const int cur = m & 1;
    uint r0v=0,r1v=0,r2v=0,r3v=0,r4v=0,r5v=0,r6v=0,r7v=0,r8v=0;
    if (m < 4) {
      const ushort* mp = mats[m+1];
      r0v = *(const uint*)&mp[2*t];          r1v = *(const uint*)&mp[2*(t+256)];
      r2v = *(const uint*)&mp[2*(t+512)];    r3v = *(const uint*)&mp[2*(t+768)];
      r4v = *(const uint*)&mp[2*(t+1024)];   r5v = *(const uint*)&mp[2*(t+1280)];
      r6v = *(const uint*)&mp[2*(t+1536)];   r7v = *(const uint*)&mp[2*(t+1792)];
      if (t < 64) r8v = *(const uint*)&mp[2*(t+2048)];
    }
    #pragma unroll
    for (int kt = 0; kt < 3; ++kt) {
      const short8 af = *(const short8*)&Xs[cur][arow*SSTR + kt*32 + koffu];
      const int T = m*3 + kt;
      #pragma unroll
      for (int tt = 0; tt < 4; ++tt) {
        const short8 bf = *(const short8*)&Wp[(((size_t)tt*15 + T)*64 + l)*8];
        acc[tt] = __builtin_amdgcn_mfma_f32_16x16x32_f16(af, bf, acc[tt], 0, 0, 0);
      }
    }
    if (m < 4) {
      ushort* nb = Xs[cur ^ 1];
      STAGE_W(nb, t,      r0v); STAGE_W(nb, t+256,  r1v);
      STAGE_W(nb, t+512,  r2v); STAGE_W(nb, t+768,  r3v);
      STAGE_W(nb, t+1024, r4v); STAGE_W(nb, t+1280, r5v);
      STAGE_W(nb, t+1536, r6v); STAGE_W(nb, t+1792, r7v);
      if (t < 64) STAGE_W(nb, t+2048, r8v);
    }
    __syncthreads();
  }
  // phase 1: c = tanh(acc+bias) -> LDS Os[b][o], fp16, stride 68
  ushort* Os = (ushort*)Xs;
  const int rg = (l >> 4) * 4;
  #pragma unroll
  for (int tt = 0; tt < 4; ++tt) {
    const int o = tt*16 + (l & 15);
    const float bs = bias[o];
    #pragma unroll
    for (int r = 0; r < 4; ++r) {
      const int b = b0 + rg + r;
      Os[b*68 + o] = f2h(tanhf(acc[tt][r] + bs));
    }
  }
  __syncthreads();
  // phase 2: out = u*h + (1-u)*c, coalesced float4 stores (h from fp16 hxh)
  {
    const int b = t >> 2, q = t & 3;
    const ushort* hp = hxh + (size_t)b*NU + (size_t)n*Uu + q*16;
    const ushort* up = ubuf + (size_t)b*NU + (size_t)n*Uu + q*16;
    float* op = out + (size_t)b*NU + (size_t)n*Uu + q*16;
    const ushort* os = &Os[b*68 + q*16];
    #pragma unroll
    for (int i = 0; i < 4; ++i) {
      const uint2 hv = *(const uint2*)&hp[i*4];
      const float h0 = h2f_lo(hv.x), h1 = h2f_hi(hv.x), h2 = h2f_lo(hv.y), h3 = h2f_hi(hv.y);
      const uint u01 = *(const uint*)&up[i*4];
      const uint u23 = *(const uint*)&up[i*4 + 2];
      const float u0 = h2f_lo(u01), u1 = h2f_hi(u01), u2 = h2f_lo(u23), u3 = h2f_hi(u23);
      float4 o4;
      o4.x = u0*h0 + (1.0f - u0)*__half2float(__ushort_as_half(os[i*4+0]));
      o4.y = u1*h1 + (1.0f - u1)*__half2float(__ushort_as_half(os[i*4+1]));
      o4.z = u2*h2 + (1.0f - u2)*__half2float(__ushort_as_half(os[i*4+2]));
      o4.w = u3*h3 + (1.0f - u3)*__half2float(__ushort_as_half(os[i*4+3]));
      *(float4*)&op[i*4] = o4;
    }
  }
}

extern "C" void kernel_launch(void* const* d_in, const int* in_sizes, int n_in,
                              void* d_out, int out_size, void* d_ws, size_t ws_size,
                              hipStream_t stream) {
  const float* inp = (const float*)d_in[0];
  const float* hx  = (const float*)d_in[1];
  const float* sup = (const float*)d_in[2];
  const float* ruW = (const float*)d_in[3];
  const float* ruB = (const float*)d_in[4];
  const float* gW  = (const float*)d_in[5];
  const float* gB  = (const float*)d_in[6];
  float* out = (float*)d_out;

  // workspace: x0 | y1[2] | y2[2] | u | hxh | Wpk | ELL(row) | ELL(col)+pad | rcnt | rcp
  ushort* x0   = (ushort*)d_ws;
  ushort* y1   = x0 + MATSZ;
  ushort* y2   = y1 + 2*MATSZ;
  ushort* ubuf = y2 + 2*MATSZ;
  ushort* hxh  = ubuf + (size_t)Bb*NU;
  ushort* Wp1  = hxh + (size_t)Bb*NU;
  ushort* Wp2  = Wp1 + 61440;
  uint* pkv  = (uint*)(Wp2 + 30720);
  uint* pT   = pkv + (size_t)8192*ELLW;
  int*  rcnt = (int*)(pT + (size_t)8192*(ELLW + 4));   // +4: prefetch overrun pad
  uint* rcp  = (uint*)(rcnt + 8192);

  k_fill<<<2048, 256, 0, stream>>>(sup, pkv, rcnt);
  k_perm<<<2, 1024, 0, stream>>>(rcnt, rcp);
  k_tr<<<128, 256, 0, stream>>>(pkv, rcp, pT);
  k_wpack<<<360, 256, 0, stream>>>(ruW, gW, Wp1, Wp2);
  k_bx0<<<Nn, 256, 0, stream>>>(inp, hx, x0, hxh);

  // gconv1
  k_spmm<false><<<512, 1024, 0, stream>>>(x0, nullptr, y1, rcp, pT);
  k_spmm<true ><<<512, 1024, 0, stream>>>(y1, x0,      y2, rcp, pT);
  k_gemm1<<<Nn, 256, 0, stream>>>(x0, y1, y2, Wp1, ruB, hxh, x0, ubuf);
  // gconv2 (x0 state slots now hold fp16(r*hx))
  k_spmm<false><<<512, 1024, 0, stream>>>(x0, nullptr, y1, rcp, pT);
  k_spmm<true ><<<512, 1024, 0, stream>>>(y1, x0,      y2, rcp, pT);
  k_gemm2<<<Nn, 256, 0, stream>>>(x0, y1, y2, Wp2, gB, hxh, ubuf, out);
}

// Round 24
// 708.624 us; speedup vs baseline: 1.0771x; 1.0251x over previous
//
#include <hip/hip_runtime.h>
#include <hip/hip_fp16.h>
#include <math.h>
#include <stdint.h>

#define Bb 64
#define Nn 4096
#define Uu 64
#define RL 4224                         // 64*66
#define NU (Nn*Uu)
#define MATSZ ((size_t)Nn*(size_t)RL)   // elements per feature matrix
#define ELLW 112                        // ELL row capacity (avg nnz ~42), multiple of 4
#define SSTR 104                        // gemm slab k-stride: 96 (3 K-tiles) + 8 bank pad

typedef __attribute__((ext_vector_type(8))) short short8;
typedef __attribute__((ext_vector_type(4))) float f32x4;
typedef unsigned int uint;
typedef unsigned short ushort;

__device__ inline ushort f2h(float f){ return __half_as_ushort(__float2half(f)); }
__device__ inline __half2 u2h(uint u){ union{uint v;__half2 h;} c; c.v=u; return c.h; }
__device__ inline uint h2u(__half2 h){ union{__half2 h;uint v;} c; c.h=h; return c.v; }
__device__ inline float h2f_lo(uint u){ return __half2float(__ushort_as_half((ushort)(u & 0xffffu))); }
__device__ inline float h2f_hi(uint u){ return __half2float(__ushort_as_half((ushort)(u >> 16))); }

// ---------------- ELL extraction: entry = (fp16(val)<<16) | (col<<4), pad to 4 ----------------
__global__ __launch_bounds__(256) void k_fill(const float* __restrict__ sup,
                                              uint* __restrict__ pkv, int* __restrict__ rcnt) {
  const int lane = threadIdx.x & 63;
  const int row = blockIdx.x * 4 + (threadIdx.x >> 6);
  const float* rp = sup + (size_t)row * Nn;
  uint* outp = pkv + (size_t)row * ELLW;
  const unsigned long long lt = (1ull << lane) - 1ull;
  int off = 0;
  for (int j0 = 0; j0 < Nn; j0 += 64) {
    float v = rp[j0 + lane];
    unsigned long long m = __ballot(v != 0.0f);
    if (v != 0.0f) {
      int pos = off + (int)__popcll(m & lt);
      if (pos < ELLW) outp[pos] = ((uint)f2h(v) << 16) | ((uint)(j0 + lane) << 4);
    }
    off += (int)__popcll(m);
  }
  if (off > ELLW) off = ELLW;
  const int c4 = (off + 3) & ~3;
  if (lane < c4 - off) outp[off + lane] = 0u;    // val=0: contributes nothing
  if (lane == 0) rcnt[row] = c4;
}

// ---------------- nnz counting sort per support: rcp[slot] = (c4<<16) | orig_row ----------------
__global__ __launch_bounds__(1024) void k_perm(const int* __restrict__ rcnt, uint* __restrict__ rcp) {
  __shared__ int base[32];
  const int s = blockIdx.x, t = threadIdx.x;
  if (t < 32) base[t] = 0;
  __syncthreads();
  for (int r = t; r < 4096; r += 1024) atomicAdd(&base[rcnt[s*4096 + r] >> 2], 1);
  __syncthreads();
  if (t == 0) { int acc = 0; for (int i = 0; i < 32; ++i) { int h = base[i]; base[i] = acc; acc += h; } }
  __syncthreads();
  for (int r = t; r < 4096; r += 1024) {
    const int c4 = rcnt[s*4096 + r];
    const int pos = atomicAdd(&base[c4 >> 2], 1);
    rcp[s*4096 + pos] = ((uint)c4 << 16) | (uint)r;
  }
}

// ---------------- ELL transpose -> columnar pT[i][8192], PERMUTED slot order ----------------
__global__ __launch_bounds__(256) void k_tr(const uint* __restrict__ pkv, const uint* __restrict__ rcp,
                                            uint* __restrict__ pT) {
  __shared__ uint tile[64*113];
  __shared__ int rows_l[64];
  const int g = blockIdx.x, t = threadIdx.x;     // 128 blocks x 64 slots
  const int s = g >> 6;
  if (t < 64) rows_l[t] = (s << 12) | (int)(rcp[g*64 + t] & 0xffffu);
  __syncthreads();
  for (int idx = t; idx < 64*ELLW; idx += 256) {
    const int r = idx / ELLW, i = idx - r*ELLW;
    tile[r*113 + i] = pkv[(size_t)rows_l[r]*ELLW + i];
  }
  __syncthreads();
  for (int idx = t; idx < 64*ELLW; idx += 256) {
    const int i = idx >> 6, r = idx & 63;
    pT[(size_t)i*8192 + g*64 + r] = tile[r*113 + i];
  }
}

// ---------------- x0 = [inputs | hx] fp16 in [n][b][f] + hxh fp16 copy ----------------
__global__ __launch_bounds__(256) void k_bx0(const float* __restrict__ inp, const float* __restrict__ hx,
                                             ushort* __restrict__ x0, ushort* __restrict__ hxh) {
  const int n = blockIdx.x;
  const int b = threadIdx.x >> 2, q = threadIdx.x & 3;
  const float* hp = hx + (size_t)b*NU + (size_t)n*Uu + q*16;
  ushort* xp = x0 + (size_t)n*RL + b*66;
  ushort* hh = hxh + (size_t)b*NU + (size_t)n*Uu + q*16;
  #pragma unroll
  for (int i = 0; i < 4; ++i) {
    const float4 v = *(const float4*)&hp[i*4];
    const uint lo = (uint)f2h(v.x) | ((uint)f2h(v.y) << 16);
    const uint hi = (uint)f2h(v.z) | ((uint)f2h(v.w) << 16);
    const int o = 2 + q*16 + i*4;
    *(uint*)&xp[o]     = lo;
    *(uint*)&xp[o + 2] = hi;
    *(uint*)&hh[i*4]     = lo;
    *(uint*)&hh[i*4 + 2] = hi;
  }
  if (q == 0) {
    const float2 iv = *(const float2*)&inp[(size_t)b*(size_t)(Nn*2) + (size_t)n*2];
    *(uint*)&xp[0] = (uint)f2h(iv.x) | ((uint)f2h(iv.y) << 16);
  }
}

// ---------------- 4 entries: ds_read_b128 + v_pk_fma_f16 (entry-prefetch walk body) ----------------
#define PROC4E(EA, EB, EC, ED)                                                     \
  {                                                                                \
    const uint4 w0 = *(const uint4*)(slb + (EA & 0xfff0u));                        \
    const uint4 w1 = *(const uint4*)(slb + (EB & 0xfff0u));                        \
    const uint4 w2 = *(const uint4*)(slb + (EC & 0xfff0u));                        \
    const uint4 w3 = *(const uint4*)(slb + (ED & 0xfff0u));                        \
    const __half2 av0 = u2h(__builtin_amdgcn_perm(EA, EA, 0x03020302u));           \
    const __half2 av1 = u2h(__builtin_amdgcn_perm(EB, EB, 0x03020302u));           \
    const __half2 av2 = u2h(__builtin_amdgcn_perm(EC, EC, 0x03020302u));           \
    const __half2 av3 = u2h(__builtin_amdgcn_perm(ED, ED, 0x03020302u));           \
    a01 = __hfma2(av0, u2h(w0.x), a01); a23 = __hfma2(av0, u2h(w0.y), a23);        \
    a45 = __hfma2(av0, u2h(w0.z), a45); a67 = __hfma2(av0, u2h(w0.w), a67);        \
    a01 = __hfma2(av1, u2h(w1.x), a01); a23 = __hfma2(av1, u2h(w1.y), a23);        \
    a45 = __hfma2(av1, u2h(w1.z), a45); a67 = __hfma2(av1, u2h(w1.w), a67);        \
    a01 = __hfma2(av2, u2h(w2.x), a01); a23 = __hfma2(av2, u2h(w2.y), a23);        \
    a45 = __hfma2(av2, u2h(w2.z), a45); a67 = __hfma2(av2, u2h(w2.w), a67);        \
    a01 = __hfma2(av3, u2h(w3.x), a01); a23 = __hfma2(av3, u2h(w3.y), a23);        \
    a45 = __hfma2(av3, u2h(w3.z), a45); a67 = __hfma2(av3, u2h(w3.w), a67);        \
  }

// core walk: slot RB -> accumulators a01..a67 (entry prefetch-1)
#define WALKCORE(RB, N4)                                                           \
    const uint* pp = pT + (RB);                                                    \
    __half2 a01 = u2h(0), a23 = u2h(0), a45 = u2h(0), a67 = u2h(0);                \
    uint e0=pp[0], e1=pp[8192], e2=pp[16384], e3=pp[24576]; pp += 32768;           \
    for (int i = 1; i < (N4); ++i) {                                               \
      const uint f0=pp[0], f1=pp[8192], f2=pp[16384], f3=pp[24576]; pp += 32768;   \
      PROC4E(e0, e1, e2, e3);                                                      \
      e0=f0; e1=f1; e2=f2; e3=f3;                                                  \
    }                                                                              \
    PROC4E(e0, e1, e2, e3);

// ---------------- fused gconv (primary 512 units): y1 = A@x (regs+global), y2 = 2A@y1 - x ----
// Per support: stage x slab -> walk1 (y1 kept in 16 VGPRs, coalesced global store) ->
// barrier -> ds_write y1 into slab (overwrite x) -> barrier -> walk2 from y1-slab with
// x re-read from global (same per-lane pattern the old pass2 used). Kills the y1
// global restage and one dispatch round.
__global__ __launch_bounds__(1024, 8) void k_gconv(const ushort* __restrict__ x0m,
                                                   ushort* __restrict__ y1, ushort* __restrict__ y2,
                                                   const uint* __restrict__ rcp,
                                                   const uint* __restrict__ pT) {
  __shared__ ushort slab[4096*8];                        // 64 KiB, 16B rows
  const char* slb = (const char*)slab;
  const int t = threadIdx.x, b = blockIdx.x;
  const int unit = ((b & 7) << 6) + (b >> 3);
  const int c0 = unit * 8;
  #pragma unroll 1
  for (int s = 0; s < 2; ++s) {
    if (s) __syncthreads();                              // walk2 slab reads done
    #pragma unroll
    for (int it = 0; it < 4; ++it) {                     // stage x
      const int j = it * 1024 + t;
      *(uint4*)&slab[j * 8] = *(const uint4*)&x0m[(size_t)j * RL + c0];
    }
    __syncthreads();
    const int sb = s << 12;
    ushort* yo1 = y1 + (size_t)s * MATSZ + c0;
    ushort* yo2 = y2 + (size_t)s * MATSZ + c0;
    uint4 yv[4]; int rw[4];
    #pragma unroll
    for (int k = 0; k < 4; ++k) {                        // walk1: 4 slots/thread
      const int rb = sb + k*1024 + t;
      const uint rc = rcp[rb];
      const int n4 = (int)(rc >> 18);
      rw[k] = (int)(rc & 0xffffu);
      WALKCORE(rb, n4);
      uint4 o; o.x = h2u(a01); o.y = h2u(a23); o.z = h2u(a45); o.w = h2u(a67);
      yv[k] = o;
      *(uint4*)&yo1[(size_t)rw[k] * RL] = o;             // y1 global (for gemm)
    }
    __syncthreads();                                     // all walk1 slab reads done
    #pragma unroll
    for (int k = 0; k < 4; ++k) *(uint4*)&slab[rw[k] * 8] = yv[k];   // slab := y1
    __syncthreads();
    #pragma unroll 1
    for (int k = 0; k < 4; ++k) {                        // walk2: Chebyshev
      const int rb = sb + k*1024 + t;
      const uint rc = rcp[rb];
      const int n4 = (int)(rc >> 18);
      const int row = (int)(rc & 0xffffu);
      WALKCORE(rb, n4);
      const uint4 xv = *(const uint4*)&x0m[(size_t)row * RL + c0];
      uint4 o;
      o.x = h2u(__hsub2(__hadd2(a01, a01), u2h(xv.x)));
      o.y = h2u(__hsub2(__hadd2(a23, a23), u2h(xv.y)));
      o.z = h2u(__hsub2(__hadd2(a45, a45), u2h(xv.z)));
      o.w = h2u(__hsub2(__hadd2(a67, a67), u2h(xv.w)));
      *(uint4*)&yo2[(size_t)row * RL] = o;
    }
  }
}

// ---------------- leftover SpMM (16 units, row-split 128x32), old 2-pass scheme ----------------
template<bool PASS2>
__global__ __launch_bounds__(1024, 8) void k_spmmL(const ushort* __restrict__ xin,
                                                   const ushort* __restrict__ xsub,
                                                   ushort* __restrict__ yout,
                                                   const uint* __restrict__ rcp,
                                                   const uint* __restrict__ pT) {
  __shared__ ushort slab[4096*8];
  const char* slb = (const char*)slab;
  const int t = threadIdx.x, b = blockIdx.x;             // grid 512
  const int unit = 512 + (b >> 5), r0 = (b & 31) * 128;
  const int c0 = unit * 8;
  #pragma unroll 1
  for (int s = 0; s < 2; ++s) {
    if (PASS2 || s == 0) {
      if (s) __syncthreads();
      const ushort* src = xin + (PASS2 ? (size_t)s * MATSZ : (size_t)0) + c0;
      #pragma unroll
      for (int it = 0; it < 4; ++it) {
        const int j = it * 1024 + t;
        *(uint4*)&slab[j * 8] = *(const uint4*)&src[(size_t)j * RL];
      }
      __syncthreads();
    }
    const int sb = s << 12;
    ushort* yo = yout + (size_t)s * MATSZ + c0;
    if (t < 128) {
      const int rb = sb + r0 + t;
      const uint rc = rcp[rb];
      const int n4 = (int)(rc >> 18);
      const int row = (int)(rc & 0xffffu);
      WALKCORE(rb, n4);
      uint4 o;
      if (PASS2) {
        const uint4 xv = *(const uint4*)&xsub[(size_t)row * RL + c0];
        o.x = h2u(__hsub2(__hadd2(a01, a01), u2h(xv.x)));
        o.y = h2u(__hsub2(__hadd2(a23, a23), u2h(xv.y)));
        o.z = h2u(__hsub2(__hadd2(a45, a45), u2h(xv.z)));
        o.w = h2u(__hsub2(__hadd2(a67, a67), u2h(xv.w)));
      } else {
        o.x = h2u(a01); o.y = h2u(a23); o.z = h2u(a45); o.w = h2u(a67);
      }
      *(uint4*)&yo[(size_t)row * RL] = o;
    }
  }
}

// ---------------- W pre-pack, slab order: T = m*3+kt, k_in_slab f = kt*32+koffu+i ----------------
__global__ __launch_bounds__(256) void k_wpack(const float* __restrict__ W1, const float* __restrict__ W2,
                                               ushort* __restrict__ Wp1, ushort* __restrict__ Wp2) {
  const int tid = blockIdx.x*256 + threadIdx.x;      // grid 360 -> 92160
  const int i = tid & 7, l = (tid >> 3) & 63;
  const int koffu = (l >> 4) * 8;
  if (tid < 61440) {
    const int g = tid >> 9, tt = g / 15, T = g % 15;
    const int m = T / 3, kt = T % 3;
    const int f = kt*32 + koffu + i;
    const int c = tt*16 + (l & 15);
    Wp1[tid] = (f < 66) ? f2h(W1[(size_t)(f*5 + m)*128 + c]) : (ushort)0;
  } else {
    const int t2 = tid - 61440;
    const int g = t2 >> 9, tt = g / 15, T = g % 15;
    const int m = T / 3, kt = T % 3;
    const int f = kt*32 + koffu + i;
    const int c = tt*16 + (l & 15);
    Wp2[t2] = (f < 66) ? f2h(W2[(size_t)(f*5 + m)*64 + c]) : (ushort)0;
  }
}

// slab source: contiguous 4224 ushorts = 2112 uints; scatter to Xs[b*104+f] (f even -> 4B aligned)
#define STAGE_W(DST, J, V) { const int q_=2*(J), b_=q_/66, f_=q_-66*b_; *(uint*)&(DST)[b_*SSTR+f_] = (V); }

// ---------------- gconv1 output GEMM (slab-pipelined, MFMA f16), sigmoid + r*hx + u ----------------
__global__ __launch_bounds__(256, 6) void k_gemm1(const ushort* __restrict__ x0, const ushort* __restrict__ y1,
                                                  const ushort* __restrict__ y2, const ushort* __restrict__ Wp,
                                                  const float* __restrict__ bias, const ushort* __restrict__ hxh,
                                                  ushort* __restrict__ x0w, ushort* __restrict__ ubuf) {
  __shared__ ushort Xs[2][64*SSTR];                // 26.6 KiB -> 6 blocks/CU
  const int n = blockIdx.x, t = threadIdx.x;
  for (int q = t; q < 2*64*SSTR/4; q += 256) ((unsigned long long*)Xs)[q] = 0ull;  // pads stay 0
  __syncthreads();
  const ushort* mats[5] = { x0 + (size_t)n*RL, y1 + (size_t)n*RL, y2 + (size_t)n*RL,
                            y1 + MATSZ + (size_t)n*RL, y2 + MATSZ + (size_t)n*RL };
  {
    const ushort* mp = mats[0];
    for (int j = t; j < 2112; j += 256) { const uint v = *(const uint*)&mp[2*j]; STAGE_W(Xs[0], j, v); }
  }
  __syncthreads();
  const int w = t >> 6, l = t & 63;
  const int b0 = w * 16;
  const int arow = b0 + (l & 15), koffu = (l >> 4) * 8;
  f32x4 acc[8];
  #pragma unroll
  for (int i = 0; i < 8; ++i) acc[i] = (f32x4){0.f,0.f,0.f,0.f};
  #pragma unroll
  for (int m = 0; m < 5; ++m) {
    const int cur = m & 1;
    uint r0v=0,r1v=0,r2v=0,r3v=0,r4v=0,r5v=0,r6v=0,r7v=0,r8v=0;
    if (m < 4) {                                   // prefetch next slab
      const ushort* mp = mats[m+1];
      r0v = *(const uint*)&mp[2*t];          r1v = *(const uint*)&mp[2*(t+256)];
      r2v = *(const uint*)&mp[2*(t+512)];    r3v = *(const uint*)&mp[2*(t+768)];
      r4v = *(const uint*)&mp[2*(t+1024)];   r5v = *(const uint*)&mp[2*(t+1280)];
      r6v = *(const uint*)&mp[2*(t+1536)];   r7v = *(const uint*)&mp[2*(t+1792)];
      if (t < 64) r8v = *(const uint*)&mp[2*(t+2048)];
    }
    #pragma unroll
    for (int kt = 0; kt < 3; ++kt) {
      const short8 af = *(const short8*)&Xs[cur][arow*SSTR + kt*32 + koffu];
      const int T = m*3 + kt;
      #pragma unroll
      for (int tt = 0; tt < 8; ++tt) {
        const short8 bf = *(const short8*)&Wp[(((size_t)tt*15 + T)*64 + l)*8];
        acc[tt] = __builtin_amdgcn_mfma_f32_16x16x32_f16(af, bf, acc[tt], 0, 0, 0);
      }
    }
    if (m < 4) {
      ushort* nb = Xs[cur ^ 1];
      STAGE_W(nb, t,      r0v); STAGE_W(nb, t+256,  r1v);
      STAGE_W(nb, t+512,  r2v); STAGE_W(nb, t+768,  r3v);
      STAGE_W(nb, t+1024, r4v); STAGE_W(nb, t+1280, r5v);
      STAGE_W(nb, t+1536, r6v); STAGE_W(nb, t+1792, r7v);
      if (t < 64) STAGE_W(nb, t+2048, r8v);
    }
    __syncthreads();
  }
  // phase 1: activation -> LDS Os[b][o], fp16, stride 132
  ushort* Os = (ushort*)Xs;
  const int rg = (l >> 4) * 4;
  #pragma unroll
  for (int tt = 0; tt < 8; ++tt) {
    const int o = tt*16 + (l & 15);
    const float bs = bias[o];
    #pragma unroll
    for (int r = 0; r < 4; ++r) {
      const int b = b0 + rg + r;
      const float v = acc[tt][r] + bs;
      Os[b*132 + o] = f2h(1.0f / (1.0f + __expf(-v)));
    }
  }
  __syncthreads();
  // phase 2: coalesced outputs (hx from fp16 hxh)
  {
    const int b = t >> 2, q = t & 3;
    const ushort* hp = hxh + (size_t)b*NU + (size_t)n*Uu + q*16;
    ushort* xw = x0w + (size_t)n*RL + b*66 + 2 + q*16;
    const ushort* os = &Os[b*132 + q*16];
    #pragma unroll
    for (int i = 0; i < 4; ++i) {                  // r gate: x0w = sg * hx
      const uint2 hv = *(const uint2*)&hp[i*4];
      const float h0 = h2f_lo(hv.x), h1 = h2f_hi(hv.x), h2 = h2f_lo(hv.y), h3 = h2f_hi(hv.y);
      const float s0 = __half2float(__ushort_as_half(os[i*4+0]));
      const float s1 = __half2float(__ushort_as_half(os[i*4+1]));
      const float s2 = __half2float(__ushort_as_half(os[i*4+2]));
      const float s3 = __half2float(__ushort_as_half(os[i*4+3]));
      *(uint*)&xw[i*4]     = (uint)f2h(s0*h0) | ((uint)f2h(s1*h1) << 16);
      *(uint*)&xw[i*4 + 2] = (uint)f2h(s2*h2) | ((uint)f2h(s3*h3) << 16);
    }
    ushort* uw = ubuf + (size_t)b*NU + (size_t)n*Uu + q*16;
    const ushort* os2 = &Os[b*132 + 64 + q*16];
    #pragma unroll
    for (int i = 0; i < 8; ++i) {                  // u gate
      *(uint*)&uw[i*2] = (uint)os2[i*2] | ((uint)os2[i*2+1] << 16);
    }
  }
}

// ---------------- gconv2 output GEMM (slab-pipelined, MFMA f16), tanh + final gate ----------------
__global__ __launch_bounds__(256, 6) void k_gemm2(const ushort* __restrict__ x0, const ushort* __restrict__ y1,
                                                  const ushort* __restrict__ y2, const ushort* __restrict__ Wp,
                                                  const float* __restrict__ bias, const ushort* __restrict__ hxh,
                                                  const ushort* __restrict__ ubuf, float* __restrict__ out) {
  __shared__ ushort Xs[2][64*SSTR];
  const int n = blockIdx.x, t = threadIdx.x;
  for (int q = t; q < 2*64*SSTR/4; q += 256) ((unsigned long long*)Xs)[q] = 0ull;
  __syncthreads();
  const ushort* mats[5] = { x0 + (size_t)n*RL, y1 + (size_t)n*RL, y2 + (size_t)n*RL,
                            y1 + MATSZ + (size_t)n*RL, y2 + MATSZ + (size_t)n*RL };
  {
    const ushort* mp = mats[0];
    for (int j = t; j < 2112; j += 256) { const uint v = *(const uint*)&mp[2*j]; STAGE_W(Xs[0], j, v); }
  }
  __syncthreads();
  const int w = t >> 6, l = t & 63;
  const int b0 = w * 16;
  const int arow = b0 + (l & 15), koffu = (l >> 4) * 8;
  f32x4 acc[4];
  #pragma unroll
  for (int i = 0; i < 4; ++i) acc[i] = (f32x4){0.f,0.f,0.f,0.f};
  #pragma unroll
  for (int m = 0; m < 5; ++m) {
    const int cur = m & 1;
    uint r0v=0,r1v=0,r2v=0,r3v=0,r4v=0,r5v=0,r6v=0,r7v=0,r8v=0;
    if (m < 4) {
      const ushort* mp = mats[m+1];
      r0v = *(const uint*)&mp[2*t];          r1v = *(const uint*)&mp[2*(t+256)];
      r2v = *(const uint*)&mp[2*(t+512)];    r3v = *(const uint*)&mp[2*(t+768)];
      r4v = *(const uint*)&mp[2*(t+1024)];   r5v = *(const uint*)&mp[2*(t+1280)];
      r6v = *(const uint*)&mp[2*(t+1536)];   r7v = *(const uint*)&mp[2*(t+1792)];
      if (t < 64) r8v = *(const uint*)&mp[2*(t+2048)];
    }
    #pragma unroll
    for (int kt = 0; kt < 3; ++kt) {
      const short8 af = *(const short8*)&Xs[cur][arow*SSTR + kt*32 + koffu];
      const int T = m*3 + kt;
      #pragma unroll
      for (int tt = 0; tt < 4; ++tt) {
        const short8 bf = *(const short8*)&Wp[(((size_t)tt*15 + T)*64 + l)*8];
        acc[tt] = __builtin_amdgcn_mfma_f32_16x16x32_f16(af, bf, acc[tt], 0, 0, 0);
      }
    }
    if (m < 4) {
      ushort* nb = Xs[cur ^ 1];
      STAGE_W(nb, t,      r0v); STAGE_W(nb, t+256,  r1v);
      STAGE_W(nb, t+512,  r2v); STAGE_W(nb, t+768,  r3v);
      STAGE_W(nb, t+1024, r4v); STAGE_W(nb, t+1280, r5v);
      STAGE_W(nb, t+1536, r6v); STAGE_W(nb, t+1792, r7v);
      if (t < 64) STAGE_W(nb, t+2048, r8v);
    }
    __syncthreads();
  }
  // phase 1: c = tanh(acc+bias) -> LDS Os[b][o], fp16, stride 68
  ushort* Os = (ushort*)Xs;
  const int rg = (l >> 4) * 4;
  #pragma unroll
  for (int tt = 0; tt < 4; ++tt) {
    const int o = tt*16 + (l & 15);
    const float bs = bias[o];
    #pragma unroll
    for (int r = 0; r < 4; ++r) {
      const int b = b0 + rg + r;
      Os[b*68 + o] = f2h(tanhf(acc[tt][r] + bs));
    }
  }
  __syncthreads();
  // phase 2: out = u*h + (1-u)*c, coalesced float4 stores (h from fp16 hxh)
  {
    const int b = t >> 2, q = t & 3;
    const ushort* hp = hxh + (size_t)b*NU + (size_t)n*Uu + q*16;
    const ushort* up = ubuf + (size_t)b*NU + (size_t)n*Uu + q*16;
    float* op = out + (size_t)b*NU + (size_t)n*Uu + q*16;
    const ushort* os = &Os[b*68 + q*16];
    #pragma unroll
    for (int i = 0; i < 4; ++i) {
      const uint2 hv = *(const uint2*)&hp[i*4];
      const float h0 = h2f_lo(hv.x), h1 = h2f_hi(hv.x), h2 = h2f_lo(hv.y), h3 = h2f_hi(hv.y);
      const uint u01 = *(const uint*)&up[i*4];
      const uint u23 = *(const uint*)&up[i*4 + 2];
      const float u0 = h2f_lo(u01), u1 = h2f_hi(u01), u2 = h2f_lo(u23), u3 = h2f_hi(u23);
      float4 o4;
      o4.x = u0*h0 + (1.0f - u0)*__half2float(__ushort_as_half(os[i*4+0]));
      o4.y = u1*h1 + (1.0f - u1)*__half2float(__ushort_as_half(os[i*4+1]));
      o4.z = u2*h2 + (1.0f - u2)*__half2float(__ushort_as_half(os[i*4+2]));
      o4.w = u3*h3 + (1.0f - u3)*__half2float(__ushort_as_half(os[i*4+3]));
      *(float4*)&op[i*4] = o4;
    }
  }
}

extern "C" void kernel_launch(void* const* d_in, const int* in_sizes, int n_in,
                              void* d_out, int out_size, void* d_ws, size_t ws_size,
                              hipStream_t stream) {
  const float* inp = (const float*)d_in[0];
  const float* hx  = (const float*)d_in[1];
  const float* sup = (const float*)d_in[2];
  const float* ruW = (const float*)d_in[3];
  const float* ruB = (const float*)d_in[4];
  const float* gW  = (const float*)d_in[5];
  const float* gB  = (const float*)d_in[6];
  float* out = (float*)d_out;

  // workspace: x0 | y1[2] | y2[2] | u | hxh | Wpk | ELL(row) | ELL(col)+pad | rcnt | rcp
  ushort* x0   = (ushort*)d_ws;
  ushort* y1   = x0 + MATSZ;
  ushort* y2   = y1 + 2*MATSZ;
  ushort* ubuf = y2 + 2*MATSZ;
  ushort* hxh  = ubuf + (size_t)Bb*NU;
  ushort* Wp1  = hxh + (size_t)Bb*NU;
  ushort* Wp2  = Wp1 + 61440;
  uint* pkv  = (uint*)(Wp2 + 30720);
  uint* pT   = pkv + (size_t)8192*ELLW;
  int*  rcnt = (int*)(pT + (size_t)8192*(ELLW + 4));   // +4: prefetch overrun pad
  uint* rcp  = (uint*)(rcnt + 8192);

  k_fill<<<2048, 256, 0, stream>>>(sup, pkv, rcnt);
  k_perm<<<2, 1024, 0, stream>>>(rcnt, rcp);
  k_tr<<<128, 256, 0, stream>>>(pkv, rcp, pT);
  k_wpack<<<360, 256, 0, stream>>>(ruW, gW, Wp1, Wp2);
  k_bx0<<<Nn, 256, 0, stream>>>(inp, hx, x0, hxh);

  // gconv1: fused primary units + leftover 2-pass
  k_gconv<<<512, 1024, 0, stream>>>(x0, y1, y2, rcp, pT);
  k_spmmL<false><<<512, 1024, 0, stream>>>(x0, nullptr, y1, rcp, pT);
  k_spmmL<true ><<<512, 1024, 0, stream>>>(y1, x0,      y2, rcp, pT);
  k_gemm1<<<Nn, 256, 0, stream>>>(x0, y1, y2, Wp1, ruB, hxh, x0, ubuf);
  // gconv2 (x0 state slots now hold fp16(r*hx))
  k_gconv<<<512, 1024, 0, stream>>>(x0, y1, y2, rcp, pT);
  k_spmmL<false><<<512, 1024, 0, stream>>>(x0, nullptr, y1, rcp, pT);
  k_spmmL<true ><<<512, 1024, 0, stream>>>(y1, x0,      y2, rcp, pT);
  k_gemm2<<<Nn, 256, 0, stream>>>(x0, y1, y2, Wp2, gB, hxh, ubuf, out);
}

// Round 25
// 687.845 us; speedup vs baseline: 1.1097x; 1.0302x over previous
//
#include <hip/hip_runtime.h>
#include <hip/hip_fp16.h>
#include <math.h>
#include <stdint.h>

#define Bb 64
#define Nn 4096
#define Uu 64
#define RL 4224                         // 64*66
#define NU (Nn*Uu)
#define MATSZ ((size_t)Nn*(size_t)RL)   // elements per feature matrix
#define ELLW 112                        // ELL row capacity (avg nnz ~42), multiple of 4
#define SSTR 104                        // gemm slab k-stride: 96 (3 K-tiles) + 8 bank pad

typedef __attribute__((ext_vector_type(8))) short short8;
typedef __attribute__((ext_vector_type(4))) float f32x4;
typedef unsigned int uint;
typedef unsigned short ushort;

__device__ inline ushort f2h(float f){ return __half_as_ushort(__float2half(f)); }
__device__ inline __half2 u2h(uint u){ union{uint v;__half2 h;} c; c.v=u; return c.h; }
__device__ inline uint h2u(__half2 h){ union{__half2 h;uint v;} c; c.h=h; return c.v; }
__device__ inline float h2f_lo(uint u){ return __half2float(__ushort_as_half((ushort)(u & 0xffffu))); }
__device__ inline float h2f_hi(uint u){ return __half2float(__ushort_as_half((ushort)(u >> 16))); }

// ---------------- ELL extraction: entry = (fp16(val)<<16) | (col<<4), pad to 4 ----------------
__global__ __launch_bounds__(256) void k_fill(const float* __restrict__ sup,
                                              uint* __restrict__ pkv, int* __restrict__ rcnt) {
  const int lane = threadIdx.x & 63;
  const int row = blockIdx.x * 4 + (threadIdx.x >> 6);
  const float* rp = sup + (size_t)row * Nn;
  uint* outp = pkv + (size_t)row * ELLW;
  const unsigned long long lt = (1ull << lane) - 1ull;
  int off = 0;
  for (int j0 = 0; j0 < Nn; j0 += 64) {
    float v = rp[j0 + lane];
    unsigned long long m = __ballot(v != 0.0f);
    if (v != 0.0f) {
      int pos = off + (int)__popcll(m & lt);
      if (pos < ELLW) outp[pos] = ((uint)f2h(v) << 16) | ((uint)(j0 + lane) << 4);
    }
    off += (int)__popcll(m);
  }
  if (off > ELLW) off = ELLW;
  const int c4 = (off + 3) & ~3;
  if (lane < c4 - off) outp[off + lane] = 0u;    // val=0: contributes nothing
  if (lane == 0) rcnt[row] = c4;
}

// ---------------- nnz counting sort per support: rcp[slot] = (c4<<16) | orig_row ----------------
__global__ __launch_bounds__(1024) void k_perm(const int* __restrict__ rcnt, uint* __restrict__ rcp) {
  __shared__ int base[32];
  const int s = blockIdx.x, t = threadIdx.x;
  if (t < 32) base[t] = 0;
  __syncthreads();
  for (int r = t; r < 4096; r += 1024) atomicAdd(&base[rcnt[s*4096 + r] >> 2], 1);
  __syncthreads();
  if (t == 0) { int acc = 0; for (int i = 0; i < 32; ++i) { int h = base[i]; base[i] = acc; acc += h; } }
  __syncthreads();
  for (int r = t; r < 4096; r += 1024) {
    const int c4 = rcnt[s*4096 + r];
    const int pos = atomicAdd(&base[c4 >> 2], 1);
    rcp[s*4096 + pos] = ((uint)c4 << 16) | (uint)r;
  }
}

// ---------------- ELL transpose -> columnar pT[i][8192], PERMUTED slot order ----------------
__global__ __launch_bounds__(256) void k_tr(const uint* __restrict__ pkv, const uint* __restrict__ rcp,
                                            uint* __restrict__ pT) {
  __shared__ uint tile[64*113];
  __shared__ int rows_l[64];
  const int g = blockIdx.x, t = threadIdx.x;     // 128 blocks x 64 slots
  const int s = g >> 6;
  if (t < 64) rows_l[t] = (s << 12) | (int)(rcp[g*64 + t] & 0xffffu);
  __syncthreads();
  for (int idx = t; idx < 64*ELLW; idx += 256) {
    const int r = idx / ELLW, i = idx - r*ELLW;
    tile[r*113 + i] = pkv[(size_t)rows_l[r]*ELLW + i];
  }
  __syncthreads();
  for (int idx = t; idx < 64*ELLW; idx += 256) {
    const int i = idx >> 6, r = idx & 63;
    pT[(size_t)i*8192 + g*64 + r] = tile[r*113 + i];
  }
}

// ---------------- x0 = [inputs | hx] fp16 in [n][b][f] + hxh fp16 copy ----------------
__global__ __launch_bounds__(256) void k_bx0(const float* __restrict__ inp, const float* __restrict__ hx,
                                             ushort* __restrict__ x0, ushort* __restrict__ hxh) {
  const int n = blockIdx.x;
  const int b = threadIdx.x >> 2, q = threadIdx.x & 3;
  const float* hp = hx + (size_t)b*NU + (size_t)n*Uu + q*16;
  ushort* xp = x0 + (size_t)n*RL + b*66;
  ushort* hh = hxh + (size_t)b*NU + (size_t)n*Uu + q*16;
  #pragma unroll
  for (int i = 0; i < 4; ++i) {
    const float4 v = *(const float4*)&hp[i*4];
    const uint lo = (uint)f2h(v.x) | ((uint)f2h(v.y) << 16);
    const uint hi = (uint)f2h(v.z) | ((uint)f2h(v.w) << 16);
    const int o = 2 + q*16 + i*4;
    *(uint*)&xp[o]     = lo;
    *(uint*)&xp[o + 2] = hi;
    *(uint*)&hh[i*4]     = lo;
    *(uint*)&hh[i*4 + 2] = hi;
  }
  if (q == 0) {
    const float2 iv = *(const float2*)&inp[(size_t)b*(size_t)(Nn*2) + (size_t)n*2];
    *(uint*)&xp[0] = (uint)f2h(iv.x) | ((uint)f2h(iv.y) << 16);
  }
}

// ---------------- 4 entries: ds_read_b128 + v_pk_fma_f16 (entry-prefetch walk body) ----------------
#define PROC4E(EA, EB, EC, ED)                                                     \
  {                                                                                \
    const uint4 w0 = *(const uint4*)(slb + (EA & 0xfff0u));                        \
    const uint4 w1 = *(const uint4*)(slb + (EB & 0xfff0u));                        \
    const uint4 w2 = *(const uint4*)(slb + (EC & 0xfff0u));                        \
    const uint4 w3 = *(const uint4*)(slb + (ED & 0xfff0u));                        \
    const __half2 av0 = u2h(__builtin_amdgcn_perm(EA, EA, 0x03020302u));           \
    const __half2 av1 = u2h(__builtin_amdgcn_perm(EB, EB, 0x03020302u));           \
    const __half2 av2 = u2h(__builtin_amdgcn_perm(EC, EC, 0x03020302u));           \
    const __half2 av3 = u2h(__builtin_amdgcn_perm(ED, ED, 0x03020302u));           \
    a01 = __hfma2(av0, u2h(w0.x), a01); a23 = __hfma2(av0, u2h(w0.y), a23);        \
    a45 = __hfma2(av0, u2h(w0.z), a45); a67 = __hfma2(av0, u2h(w0.w), a67);        \
    a01 = __hfma2(av1, u2h(w1.x), a01); a23 = __hfma2(av1, u2h(w1.y), a23);        \
    a45 = __hfma2(av1, u2h(w1.z), a45); a67 = __hfma2(av1, u2h(w1.w), a67);        \
    a01 = __hfma2(av2, u2h(w2.x), a01); a23 = __hfma2(av2, u2h(w2.y), a23);        \
    a45 = __hfma2(av2, u2h(w2.z), a45); a67 = __hfma2(av2, u2h(w2.w), a67);        \
    a01 = __hfma2(av3, u2h(w3.x), a01); a23 = __hfma2(av3, u2h(w3.y), a23);        \
    a45 = __hfma2(av3, u2h(w3.z), a45); a67 = __hfma2(av3, u2h(w3.w), a67);        \
  }

// core walk: slot RB -> accumulators a01..a67 (entry prefetch-1)
#define WALKCORE(RB, N4)                                                           \
    const uint* pp = pT + (RB);                                                    \
    __half2 a01 = u2h(0), a23 = u2h(0), a45 = u2h(0), a67 = u2h(0);                \
    uint e0=pp[0], e1=pp[8192], e2=pp[16384], e3=pp[24576]; pp += 32768;           \
    for (int i = 1; i < (N4); ++i) {                                               \
      const uint f0=pp[0], f1=pp[8192], f2=pp[16384], f3=pp[24576]; pp += 32768;   \
      PROC4E(e0, e1, e2, e3);                                                      \
      e0=f0; e1=f1; e2=f2; e3=f3;                                                  \
    }                                                                              \
    PROC4E(e0, e1, e2, e3);

// ---------------- fused gconv + leftover pass1 ----------------
// blocks 0..511: primary units, register-fused two-hop (y1 regs+global, y2 Chebyshev).
// blocks 512..1023: leftover units (512..527), row-chunk (128 rows) pass1 only: stage x,
// walk both supports, write y1. (Leftover pass2 needs full-unit y1 -> separate dispatch.)
__global__ __launch_bounds__(1024, 8) void k_gconv(const ushort* __restrict__ x0m,
                                                   ushort* __restrict__ y1, ushort* __restrict__ y2,
                                                   const uint* __restrict__ rcp,
                                                   const uint* __restrict__ pT) {
  __shared__ ushort slab[4096*8];                        // 64 KiB, 16B rows
  const char* slb = (const char*)slab;
  const int t = threadIdx.x, b = blockIdx.x;
  if (b < 512) {
    const int unit = ((b & 7) << 6) + (b >> 3);
    const int c0 = unit * 8;
    #pragma unroll 1
    for (int s = 0; s < 2; ++s) {
      if (s) __syncthreads();                            // walk2 slab reads done
      #pragma unroll
      for (int it = 0; it < 4; ++it) {                   // stage x
        const int j = it * 1024 + t;
        *(uint4*)&slab[j * 8] = *(const uint4*)&x0m[(size_t)j * RL + c0];
      }
      __syncthreads();
      const int sb = s << 12;
      ushort* yo1 = y1 + (size_t)s * MATSZ + c0;
      ushort* yo2 = y2 + (size_t)s * MATSZ + c0;
      uint4 yv[4]; int rw[4];
      #pragma unroll
      for (int k = 0; k < 4; ++k) {                      // walk1: 4 slots/thread
        const int rb = sb + k*1024 + t;
        const uint rc = rcp[rb];
        const int n4 = (int)(rc >> 18);
        rw[k] = (int)(rc & 0xffffu);
        WALKCORE(rb, n4);
        uint4 o; o.x = h2u(a01); o.y = h2u(a23); o.z = h2u(a45); o.w = h2u(a67);
        yv[k] = o;
        *(uint4*)&yo1[(size_t)rw[k] * RL] = o;           // y1 global (for gemm)
      }
      __syncthreads();                                   // all walk1 slab reads done
      #pragma unroll
      for (int k = 0; k < 4; ++k) *(uint4*)&slab[rw[k] * 8] = yv[k];   // slab := y1
      __syncthreads();
      #pragma unroll 1
      for (int k = 0; k < 4; ++k) {                      // walk2: Chebyshev
        const int rb = sb + k*1024 + t;
        const uint rc = rcp[rb];
        const int n4 = (int)(rc >> 18);
        const int row = (int)(rc & 0xffffu);
        WALKCORE(rb, n4);
        const uint4 xv = *(const uint4*)&x0m[(size_t)row * RL + c0];
        uint4 o;
        o.x = h2u(__hsub2(__hadd2(a01, a01), u2h(xv.x)));
        o.y = h2u(__hsub2(__hadd2(a23, a23), u2h(xv.y)));
        o.z = h2u(__hsub2(__hadd2(a45, a45), u2h(xv.z)));
        o.w = h2u(__hsub2(__hadd2(a67, a67), u2h(xv.w)));
        *(uint4*)&yo2[(size_t)row * RL] = o;
      }
    }
  } else {
    const int lb = b - 512;
    const int unit = 512 + (lb >> 5), r0 = (lb & 31) * 128;
    const int c0 = unit * 8;
    #pragma unroll
    for (int it = 0; it < 4; ++it) {                     // stage x (shared for both supports)
      const int j = it * 1024 + t;
      *(uint4*)&slab[j * 8] = *(const uint4*)&x0m[(size_t)j * RL + c0];
    }
    __syncthreads();
    #pragma unroll 1
    for (int s = 0; s < 2; ++s) {                        // pass1 only
      if (t < 128) {
        const int rb = (s << 12) + r0 + t;
        const uint rc = rcp[rb];
        const int n4 = (int)(rc >> 18);
        const int row = (int)(rc & 0xffffu);
        WALKCORE(rb, n4);
        uint4 o; o.x = h2u(a01); o.y = h2u(a23); o.z = h2u(a45); o.w = h2u(a67);
        *(uint4*)&y1[(size_t)s * MATSZ + (size_t)row * RL + c0] = o;
      }
    }
  }
}

// ---------------- leftover pass2 (16 units, row-split 128x32): y2 = 2A@y1 - x ----------------
__global__ __launch_bounds__(1024, 8) void k_spmmL2(const ushort* __restrict__ y1in,
                                                    const ushort* __restrict__ xsub,
                                                    ushort* __restrict__ yout,
                                                    const uint* __restrict__ rcp,
                                                    const uint* __restrict__ pT) {
  __shared__ ushort slab[4096*8];
  const char* slb = (const char*)slab;
  const int t = threadIdx.x, b = blockIdx.x;             // grid 512
  const int unit = 512 + (b >> 5), r0 = (b & 31) * 128;
  const int c0 = unit * 8;
  #pragma unroll 1
  for (int s = 0; s < 2; ++s) {
    if (s) __syncthreads();
    const ushort* src = y1in + (size_t)s * MATSZ + c0;
    #pragma unroll
    for (int it = 0; it < 4; ++it) {
      const int j = it * 1024 + t;
      *(uint4*)&slab[j * 8] = *(const uint4*)&src[(size_t)j * RL];
    }
    __syncthreads();
    ushort* yo = yout + (size_t)s * MATSZ + c0;
    if (t < 128) {
      const int rb = (s << 12) + r0 + t;
      const uint rc = rcp[rb];
      const int n4 = (int)(rc >> 18);
      const int row = (int)(rc & 0xffffu);
      WALKCORE(rb, n4);
      const uint4 xv = *(const uint4*)&xsub[(size_t)row * RL + c0];
      uint4 o;
      o.x = h2u(__hsub2(__hadd2(a01, a01), u2h(xv.x)));
      o.y = h2u(__hsub2(__hadd2(a23, a23), u2h(xv.y)));
      o.z = h2u(__hsub2(__hadd2(a45, a45), u2h(xv.z)));
      o.w = h2u(__hsub2(__hadd2(a67, a67), u2h(xv.w)));
      *(uint4*)&yo[(size_t)row * RL] = o;
    }
  }
}

// ---------------- W pre-pack, slab order: T = m*3+kt, k_in_slab f = kt*32+koffu+i ----------------
__global__ __launch_bounds__(256) void k_wpack(const float* __restrict__ W1, const float* __restrict__ W2,
                                               ushort* __restrict__ Wp1, ushort* __restrict__ Wp2) {
  const int tid = blockIdx.x*256 + threadIdx.x;      // grid 360 -> 92160
  const int i = tid & 7, l = (tid >> 3) & 63;
  const int koffu = (l >> 4) * 8;
  if (tid < 61440) {
    const int g = tid >> 9, tt = g / 15, T = g % 15;
    const int m = T / 3, kt = T % 3;
    const int f = kt*32 + koffu + i;
    const int c = tt*16 + (l & 15);
    Wp1[tid] = (f < 66) ? f2h(W1[(size_t)(f*5 + m)*128 + c]) : (ushort)0;
  } else {
    const int t2 = tid - 61440;
    const int g = t2 >> 9, tt = g / 15, T = g % 15;
    const int m = T / 3, kt = T % 3;
    const int f = kt*32 + koffu + i;
    const int c = tt*16 + (l & 15);
    Wp2[t2] = (f < 66) ? f2h(W2[(size_t)(f*5 + m)*64 + c]) : (ushort)0;
  }
}

// slab source: contiguous 4224 ushorts = 2112 uints; scatter to Xs[b*104+f] (f even -> 4B aligned)
#define STAGE_W(DST, J, V) { const int q_=2*(J), b_=q_/66, f_=q_-66*b_; *(uint*)&(DST)[b_*SSTR+f_] = (V); }

// ---------------- gconv1 output GEMM (slab-pipelined, MFMA f16), sigmoid + r*hx + u ----------------
__global__ __launch_bounds__(256, 6) void k_gemm1(const ushort* __restrict__ x0, const ushort* __restrict__ y1,
                                                  const ushort* __restrict__ y2, const ushort* __restrict__ Wp,
                                                  const float* __restrict__ bias, const ushort* __restrict__ hxh,
                                                  ushort* __restrict__ x0w, ushort* __restrict__ ubuf) {
  __shared__ ushort Xs[2][64*SSTR];                // 26.6 KiB -> 6 blocks/CU
  const int n = blockIdx.x, t = threadIdx.x;
  for (int q = t; q < 2*64*SSTR/4; q += 256) ((unsigned long long*)Xs)[q] = 0ull;  // pads stay 0
  __syncthreads();
  const ushort* mats[5] = { x0 + (size_t)n*RL, y1 + (size_t)n*RL, y2 + (size_t)n*RL,
                            y1 + MATSZ + (size_t)n*RL, y2 + MATSZ + (size_t)n*RL };
  {
    const ushort* mp = mats[0];
    for (int j = t; j < 2112; j += 256) { const uint v = *(const uint*)&mp[2*j]; STAGE_W(Xs[0], j, v); }
  }
  __syncthreads();
  const int w = t >> 6, l = t & 63;
  const int b0 = w * 16;
  const int arow = b0 + (l & 15), koffu = (l >> 4) * 8;
  f32x4 acc[8];
  #pragma unroll
  for (int i = 0; i < 8; ++i) acc[i] = (f32x4){0.f,0.f,0.f,0.f};
  #pragma unroll
  for (int m = 0; m < 5; ++m) {
    const int cur = m & 1;
    uint r0v=0,r1v=0,r2v=0,r3v=0,r4v=0,r5v=0,r6v=0,r7v=0,r8v=0;
    if (m < 4) {                                   // prefetch next slab
      const ushort* mp = mats[m+1];
      r0v = *(const uint*)&mp[2*t];          r1v = *(const uint*)&mp[2*(t+256)];
      r2v = *(const uint*)&mp[2*(t+512)];    r3v = *(const uint*)&mp[2*(t+768)];
      r4v = *(const uint*)&mp[2*(t+1024)];   r5v = *(const uint*)&mp[2*(t+1280)];
      r6v = *(const uint*)&mp[2*(t+1536)];   r7v = *(const uint*)&mp[2*(t+1792)];
      if (t < 64) r8v = *(const uint*)&mp[2*(t+2048)];
    }
    #pragma unroll
    for (int kt = 0; kt < 3; ++kt) {
      const short8 af = *(const short8*)&Xs[cur][arow*SSTR + kt*32 + koffu];
      const int T = m*3 + kt;
      #pragma unroll
      for (int tt = 0; tt < 8; ++tt) {
        const short8 bf = *(const short8*)&Wp[(((size_t)tt*15 + T)*64 + l)*8];
        acc[tt] = __builtin_amdgcn_mfma_f32_16x16x32_f16(af, bf, acc[tt], 0, 0, 0);
      }
    }
    if (m < 4) {
      ushort* nb = Xs[cur ^ 1];
      STAGE_W(nb, t,      r0v); STAGE_W(nb, t+256,  r1v);
      STAGE_W(nb, t+512,  r2v); STAGE_W(nb, t+768,  r3v);
      STAGE_W(nb, t+1024, r4v); STAGE_W(nb, t+1280, r5v);
      STAGE_W(nb, t+1536, r6v); STAGE_W(nb, t+1792, r7v);
      if (t < 64) STAGE_W(nb, t+2048, r8v);
    }
    __syncthreads();
  }
  // phase 1: activation -> LDS Os[b][o], fp16, stride 132
  ushort* Os = (ushort*)Xs;
  const int rg = (l >> 4) * 4;
  #pragma unroll
  for (int tt = 0; tt < 8; ++tt) {
    const int o = tt*16 + (l & 15);
    const float bs = bias[o];
    #pragma unroll
    for (int r = 0; r < 4; ++r) {
      const int b = b0 + rg + r;
      const float v = acc[tt][r] + bs;
      Os[b*132 + o] = f2h(1.0f / (1.0f + __expf(-v)));
    }
  }
  __syncthreads();
  // phase 2: coalesced outputs (hx from fp16 hxh)
  {
    const int b = t >> 2, q = t & 3;
    const ushort* hp = hxh + (size_t)b*NU + (size_t)n*Uu + q*16;
    ushort* xw = x0w + (size_t)n*RL + b*66 + 2 + q*16;
    const ushort* os = &Os[b*132 + q*16];
    #pragma unroll
    for (int i = 0; i < 4; ++i) {                  // r gate: x0w = sg * hx
      const uint2 hv = *(const uint2*)&hp[i*4];
      const float h0 = h2f_lo(hv.x), h1 = h2f_hi(hv.x), h2 = h2f_lo(hv.y), h3 = h2f_hi(hv.y);
      const float s0 = __half2float(__ushort_as_half(os[i*4+0]));
      const float s1 = __half2float(__ushort_as_half(os[i*4+1]));
      const float s2 = __half2float(__ushort_as_half(os[i*4+2]));
      const float s3 = __half2float(__ushort_as_half(os[i*4+3]));
      *(uint*)&xw[i*4]     = (uint)f2h(s0*h0) | ((uint)f2h(s1*h1) << 16);
      *(uint*)&xw[i*4 + 2] = (uint)f2h(s2*h2) | ((uint)f2h(s3*h3) << 16);
    }
    ushort* uw = ubuf + (size_t)b*NU + (size_t)n*Uu + q*16;
    const ushort* os2 = &Os[b*132 + 64 + q*16];
    #pragma unroll
    for (int i = 0; i < 8; ++i) {                  // u gate
      *(uint*)&uw[i*2] = (uint)os2[i*2] | ((uint)os2[i*2+1] << 16);
    }
  }
}

// ---------------- gconv2 output GEMM (slab-pipelined, MFMA f16), tanh + final gate ----------------
__global__ __launch_bounds__(256, 6) void k_gemm2(const ushort* __restrict__ x0, const ushort* __restrict__ y1,
                                                  const ushort* __restrict__ y2, const ushort* __restrict__ Wp,
                                                  const float* __restrict__ bias, const ushort* __restrict__ hxh,
                                                  const ushort* __restrict__ ubuf, float* __restrict__ out) {
  __shared__ ushort Xs[2][64*SSTR];
  const int n = blockIdx.x, t = threadIdx.x;
  for (int q = t; q < 2*64*SSTR/4; q += 256) ((unsigned long long*)Xs)[q] = 0ull;
  __syncthreads();
  const ushort* mats[5] = { x0 + (size_t)n*RL, y1 + (size_t)n*RL, y2 + (size_t)n*RL,
                            y1 + MATSZ + (size_t)n*RL, y2 + MATSZ + (size_t)n*RL };
  {
    const ushort* mp = mats[0];
    for (int j = t; j < 2112; j += 256) { const uint v = *(const uint*)&mp[2*j]; STAGE_W(Xs[0], j, v); }
  }
  __syncthreads();
  const int w = t >> 6, l = t & 63;
  const int b0 = w * 16;
  const int arow = b0 + (l & 15), koffu = (l >> 4) * 8;
  f32x4 acc[4];
  #pragma unroll
  for (int i = 0; i < 4; ++i) acc[i] = (f32x4){0.f,0.f,0.f,0.f};
  #pragma unroll
  for (int m = 0; m < 5; ++m) {
    const int cur = m & 1;
    uint r0v=0,r1v=0,r2v=0,r3v=0,r4v=0,r5v=0,r6v=0,r7v=0,r8v=0;
    if (m < 4) {
      const ushort* mp = mats[m+1];
      r0v = *(const uint*)&mp[2*t];          r1v = *(const uint*)&mp[2*(t+256)];
      r2v = *(const uint*)&mp[2*(t+512)];    r3v = *(const uint*)&mp[2*(t+768)];
      r4v = *(const uint*)&mp[2*(t+1024)];   r5v = *(const uint*)&mp[2*(t+1280)];
      r6v = *(const uint*)&mp[2*(t+1536)];   r7v = *(const uint*)&mp[2*(t+1792)];
      if (t < 64) r8v = *(const uint*)&mp[2*(t+2048)];
    }
    #pragma unroll
    for (int kt = 0; kt < 3; ++kt) {
      const short8 af = *(const short8*)&Xs[cur][arow*SSTR + kt*32 + koffu];
      const int T = m*3 + kt;
      #pragma unroll
      for (int tt = 0; tt < 4; ++tt) {
        const short8 bf = *(const short8*)&Wp[(((size_t)tt*15 + T)*64 + l)*8];
        acc[tt] = __builtin_amdgcn_mfma_f32_16x16x32_f16(af, bf, acc[tt], 0, 0, 0);
      }
    }
    if (m < 4) {
      ushort* nb = Xs[cur ^ 1];
      STAGE_W(nb, t,      r0v); STAGE_W(nb, t+256,  r1v);
      STAGE_W(nb, t+512,  r2v); STAGE_W(nb, t+768,  r3v);
      STAGE_W(nb, t+1024, r4v); STAGE_W(nb, t+1280, r5v);
      STAGE_W(nb, t+1536, r6v); STAGE_W(nb, t+1792, r7v);
      if (t < 64) STAGE_W(nb, t+2048, r8v);
    }
    __syncthreads();
  }
  // phase 1: c = tanh(acc+bias) -> LDS Os[b][o], fp16, stride 68
  ushort* Os = (ushort*)Xs;
  const int rg = (l >> 4) * 4;
  #pragma unroll
  for (int tt = 0; tt < 4; ++tt) {
    const int o = tt*16 + (l & 15);
    const float bs = bias[o];
    #pragma unroll
    for (int r = 0; r < 4; ++r) {
      const int b = b0 + rg + r;
      Os[b*68 + o] = f2h(tanhf(acc[tt][r] + bs));
    }
  }
  __syncthreads();
  // phase 2: out = u*h + (1-u)*c, coalesced float4 stores (h from fp16 hxh)
  {
    const int b = t >> 2, q = t & 3;
    const ushort* hp = hxh + (size_t)b*NU + (size_t)n*Uu + q*16;
    const ushort* up = ubuf + (size_t)b*NU + (size_t)n*Uu + q*16;
    float* op = out + (size_t)b*NU + (size_t)n*Uu + q*16;
    const ushort* os = &Os[b*68 + q*16];
    #pragma unroll
    for (int i = 0; i < 4; ++i) {
      const uint2 hv = *(const uint2*)&hp[i*4];
      const float h0 = h2f_lo(hv.x), h1 = h2f_hi(hv.x), h2 = h2f_lo(hv.y), h3 = h2f_hi(hv.y);
      const uint u01 = *(const uint*)&up[i*4];
      const uint u23 = *(const uint*)&up[i*4 + 2];
      const float u0 = h2f_lo(u01), u1 = h2f_hi(u01), u2 = h2f_lo(u23), u3 = h2f_hi(u23);
      float4 o4;
      o4.x = u0*h0 + (1.0f - u0)*__half2float(__ushort_as_half(os[i*4+0]));
      o4.y = u1*h1 + (1.0f - u1)*__half2float(__ushort_as_half(os[i*4+1]));
      o4.z = u2*h2 + (1.0f - u2)*__half2float(__ushort_as_half(os[i*4+2]));
      o4.w = u3*h3 + (1.0f - u3)*__half2float(__ushort_as_half(os[i*4+3]));
      *(float4*)&op[i*4] = o4;
    }
  }
}

extern "C" void kernel_launch(void* const* d_in, const int* in_sizes, int n_in,
                              void* d_out, int out_size, void* d_ws, size_t ws_size,
                              hipStream_t stream) {
  const float* inp = (const float*)d_in[0];
  const float* hx  = (const float*)d_in[1];
  const float* sup = (const float*)d_in[2];
  const float* ruW = (const float*)d_in[3];
  const float* ruB = (const float*)d_in[4];
  const float* gW  = (const float*)d_in[5];
  const float* gB  = (const float*)d_in[6];
  float* out = (float*)d_out;

  // workspace: x0 | y1[2] | y2[2] | u | hxh | Wpk | ELL(row) | ELL(col)+pad | rcnt | rcp
  ushort* x0   = (ushort*)d_ws;
  ushort* y1   = x0 + MATSZ;
  ushort* y2   = y1 + 2*MATSZ;
  ushort* ubuf = y2 + 2*MATSZ;
  ushort* hxh  = ubuf + (size_t)Bb*NU;
  ushort* Wp1  = hxh + (size_t)Bb*NU;
  ushort* Wp2  = Wp1 + 61440;
  uint* pkv  = (uint*)(Wp2 + 30720);
  uint* pT   = pkv + (size_t)8192*ELLW;
  int*  rcnt = (int*)(pT + (size_t)8192*(ELLW + 4));   // +4: prefetch overrun pad
  uint* rcp  = (uint*)(rcnt + 8192);

  k_fill<<<2048, 256, 0, stream>>>(sup, pkv, rcnt);
  k_perm<<<2, 1024, 0, stream>>>(rcnt, rcp);
  k_tr<<<128, 256, 0, stream>>>(pkv, rcp, pT);
  k_wpack<<<360, 256, 0, stream>>>(ruW, gW, Wp1, Wp2);
  k_bx0<<<Nn, 256, 0, stream>>>(inp, hx, x0, hxh);

  // gconv1: fused primary + leftover pass1 in one dispatch; leftover pass2 separate
  k_gconv<<<1024, 1024, 0, stream>>>(x0, y1, y2, rcp, pT);
  k_spmmL2<<<512, 1024, 0, stream>>>(y1, x0, y2, rcp, pT);
  k_gemm1<<<Nn, 256, 0, stream>>>(x0, y1, y2, Wp1, ruB, hxh, x0, ubuf);
  // gconv2 (x0 state slots now hold fp16(r*hx))
  k_gconv<<<1024, 1024, 0, stream>>>(x0, y1, y2, rcp, pT);
  k_spmmL2<<<512, 1024, 0, stream>>>(y1, x0, y2, rcp, pT);
  k_gemm2<<<Nn, 256, 0, stream>>>(x0, y1, y2, Wp2, gB, hxh, ubuf, out);
}